// Round 1
// baseline (4229.368 us; speedup 1.0000x reference)
//
#include <hip/hip_runtime.h>
#include <math.h>

#define N_DET 512
#define N_TRK 512
#define NPTS  256

__device__ __forceinline__ float sigm(float x) { return 1.f / (1.f + expf(-x)); }

// ---------------------------------------------------------------------------
// PointNet: per box (1024 boxes), 256 threads = 1 point each.
// MLP 3->64->128->128 (relu), maxpool over 256 points -> h[box][0:128]
// Weights read with uniform (scalar) loads; h1/h2 live in registers with
// fully static indexing (unrolled loops).
// ---------------------------------------------------------------------------
__global__ __launch_bounds__(256) void pointnet_kernel(
    const float* __restrict__ det_pc, const float* __restrict__ trk_pc,
    const float* __restrict__ w1, const float* __restrict__ b1,
    const float* __restrict__ w2, const float* __restrict__ b2,
    const float* __restrict__ w3, const float* __restrict__ b3,
    float* __restrict__ hout)
{
    const int box = blockIdx.x;
    const int p   = threadIdx.x;
    const float* pc = (box < N_DET) ? (det_pc + ((size_t)box * NPTS + p) * 3)
                                    : (trk_pc + ((size_t)(box - N_DET) * NPTS + p) * 3);
    const float x = pc[0], y = pc[1], z = pc[2];

    float h1[64];
#pragma unroll
    for (int o = 0; o < 64; ++o) {
        float s = b1[o];
        s = fmaf(w1[o*3+0], x, s);
        s = fmaf(w1[o*3+1], y, s);
        s = fmaf(w1[o*3+2], z, s);
        h1[o] = fmaxf(s, 0.f);
    }

    float h2[128];
#pragma unroll
    for (int o = 0; o < 128; ++o) {
        float a0 = 0.f, a1 = 0.f, a2 = 0.f, a3 = 0.f;
        const float* wr = w2 + o*64;
#pragma unroll
        for (int c = 0; c < 64; c += 4) {
            a0 = fmaf(wr[c+0], h1[c+0], a0);
            a1 = fmaf(wr[c+1], h1[c+1], a1);
            a2 = fmaf(wr[c+2], h1[c+2], a2);
            a3 = fmaf(wr[c+3], h1[c+3], a3);
        }
        h2[o] = fmaxf(b2[o] + ((a0+a1)+(a2+a3)), 0.f);
    }

    __shared__ float wmax[4][128];
    const int wave = threadIdx.x >> 6, lane = threadIdx.x & 63;
    for (int o = 0; o < 128; ++o) {   // o dynamic is fine: only weight addrs depend on it
        float a0 = 0.f, a1 = 0.f, a2 = 0.f, a3 = 0.f;
        const float* wr = w3 + o*128;
#pragma unroll
        for (int c = 0; c < 128; c += 4) {
            a0 = fmaf(wr[c+0], h2[c+0], a0);
            a1 = fmaf(wr[c+1], h2[c+1], a1);
            a2 = fmaf(wr[c+2], h2[c+2], a2);
            a3 = fmaf(wr[c+3], h2[c+3], a3);
        }
        float s = fmaxf(b3[o] + ((a0+a1)+(a2+a3)), 0.f);
#pragma unroll
        for (int off = 32; off > 0; off >>= 1)
            s = fmaxf(s, __shfl_xor(s, off, 64));
        if (lane == 0) wmax[wave][o] = s;
    }
    __syncthreads();
    if (threadIdx.x < 128) {
        const int o = threadIdx.x;
        const float m = fmaxf(fmaxf(wmax[0][o], wmax[1][o]), fmaxf(wmax[2][o], wmax[3][o]));
        hout[(size_t)box * 256 + o] = m;
    }
}

// ---------------------------------------------------------------------------
// det motion MLP: 9 -> 64 (relu) -> 128 (no final relu). One block per det.
// ---------------------------------------------------------------------------
__global__ __launch_bounds__(128) void detmlp_kernel(
    const float* __restrict__ boxes,
    const float* __restrict__ w1, const float* __restrict__ b1,
    const float* __restrict__ w2, const float* __restrict__ b2,
    float* __restrict__ hout)
{
    __shared__ float xb[9];
    __shared__ float h1[64];
    const int b = blockIdx.x, t = threadIdx.x;
    if (t < 9) xb[t] = boxes[b*9 + t];
    __syncthreads();
    if (t < 64) {
        float s = b1[t];
#pragma unroll
        for (int c = 0; c < 9; ++c) s = fmaf(w1[t*9+c], xb[c], s);
        h1[t] = fmaxf(s, 0.f);
    }
    __syncthreads();
    float s = b2[t];
    const float* wr = w2 + t*64;
#pragma unroll
    for (int c = 0; c < 64; ++c) s = fmaf(wr[c], h1[c], s);
    hout[(size_t)b * 256 + 128 + t] = s;
}

// ---------------------------------------------------------------------------
// 2-layer LSTM over T=10, both layers fused, 4 batches per 512-thread block.
// thread (b_loc, j) owns hidden unit j of its batch: computes gates i,f,g,o
// (rows j, 128+j, 256+j, 384+j). h staged in LDS per step.
// ---------------------------------------------------------------------------
__global__ __launch_bounds__(512) void lstm_kernel(
    const float* __restrict__ xs,    // [512][10][9]
    const float* __restrict__ wih0, const float* __restrict__ whh0, const float* __restrict__ b0,
    const float* __restrict__ wih1, const float* __restrict__ whh1, const float* __restrict__ b1,
    float* __restrict__ hout)
{
    __shared__ float h0s[4][128];
    __shared__ float h1s[4][128];
    const int bl = threadIdx.x >> 7, j = threadIdx.x & 127;
    const int batch = blockIdx.x * 4 + bl;
    float c0 = 0.f, c1 = 0.f, h1n = 0.f;
    h0s[bl][j] = 0.f;
    h1s[bl][j] = 0.f;
    __syncthreads();

    for (int t = 0; t < 10; ++t) {
        const float* xt = xs + ((size_t)batch * 10 + t) * 9;
        float g[4];
#pragma unroll
        for (int q = 0; q < 4; ++q) {
            const int row = q*128 + j;
            float s = b0[row], s2 = 0.f;
            const float* wx = wih0 + row*9;
#pragma unroll
            for (int c = 0; c < 9; ++c) s = fmaf(wx[c], xt[c], s);
            const float* wh = whh0 + row*128;
#pragma unroll
            for (int c = 0; c < 128; c += 4) {
                const float4 w = *(const float4*)(wh + c);
                const float4 h = *(const float4*)(&h0s[bl][c]);
                s  = fmaf(w.x, h.x, s);
                s2 = fmaf(w.y, h.y, s2);
                s  = fmaf(w.z, h.z, s);
                s2 = fmaf(w.w, h.w, s2);
            }
            g[q] = s + s2;
        }
        c0 = sigm(g[1]) * c0 + sigm(g[0]) * tanhf(g[2]);
        const float h0n = sigm(g[3]) * tanhf(c0);
        __syncthreads();
        h0s[bl][j] = h0n;
        __syncthreads();

#pragma unroll
        for (int q = 0; q < 4; ++q) {
            const int row = q*128 + j;
            float s = b1[row], s2 = 0.f;
            const float* wxr = wih1 + row*128;
            const float* whr = whh1 + row*128;
#pragma unroll
            for (int c = 0; c < 128; c += 4) {
                const float4 wx4 = *(const float4*)(wxr + c);
                const float4 x4  = *(const float4*)(&h0s[bl][c]);
                const float4 wh4 = *(const float4*)(whr + c);
                const float4 hh4 = *(const float4*)(&h1s[bl][c]);
                s  = fmaf(wx4.x, x4.x, s);
                s2 = fmaf(wx4.y, x4.y, s2);
                s  = fmaf(wx4.z, x4.z, s);
                s2 = fmaf(wx4.w, x4.w, s2);
                s  = fmaf(wh4.x, hh4.x, s);
                s2 = fmaf(wh4.y, hh4.y, s2);
                s  = fmaf(wh4.z, hh4.z, s);
                s2 = fmaf(wh4.w, hh4.w, s2);
            }
            g[q] = s + s2;
        }
        c1 = sigm(g[1]) * c1 + sigm(g[0]) * tanhf(g[2]);
        h1n = sigm(g[3]) * tanhf(c1);
        __syncthreads();
        h1s[bl][j] = h1n;
        __syncthreads();
    }
    hout[(size_t)(N_DET + batch) * 256 + 128 + j] = h1n;
}

// ---------------------------------------------------------------------------
// EdgeConv fused GEMM: C[1024][512] = h @ [tw;pw]^T with routing epilogue.
//   cols   0..255 -> theta: det rows -> Abuf, trk rows -> Bbuf
//   cols 256..511 -> phi+pb: det rows -> hnext = relu(phi+tb); trk -> phiT
// 64x64 tile per 256-thread block, 4x4 per thread, k-major LDS tiles.
// ---------------------------------------------------------------------------
__global__ __launch_bounds__(256) void ec_gemm_kernel(
    const float* __restrict__ hin,
    const float* __restrict__ tw, const float* __restrict__ tb,
    const float* __restrict__ pw, const float* __restrict__ pb,
    float* __restrict__ Abuf, float* __restrict__ Bbuf,
    float* __restrict__ phiT, float* __restrict__ hnext)
{
    __shared__ float As[16][68];
    __shared__ float Ws[16][68];
    const int bm = blockIdx.x, bn = blockIdx.y;
    const int tid = threadIdx.x;
    const int tx = tid & 15, ty = tid >> 4;
    float acc[4][4] = {};
    for (int kk = 0; kk < 256; kk += 16) {
        if (kk) __syncthreads();
#pragma unroll
        for (int i = 0; i < 4; ++i) {
            const int e = tid + 256*i;
            const int r = e >> 4, c = e & 15;
            As[c][r] = hin[(size_t)(bm*64 + r)*256 + kk + c];
            const int n = bn*64 + r;
            const float* wp = (n < 256) ? (tw + (size_t)n*256) : (pw + (size_t)(n-256)*256);
            Ws[c][r] = wp[kk + c];
        }
        __syncthreads();
#pragma unroll
        for (int k = 0; k < 16; ++k) {
            const float4 a = *(const float4*)&As[k][ty*4];
            const float4 w = *(const float4*)&Ws[k][tx*4];
            const float av[4] = {a.x, a.y, a.z, a.w};
            const float wv[4] = {w.x, w.y, w.z, w.w};
#pragma unroll
            for (int i = 0; i < 4; ++i)
#pragma unroll
                for (int jj = 0; jj < 4; ++jj)
                    acc[i][jj] = fmaf(av[i], wv[jj], acc[i][jj]);
        }
    }
    const int row0 = bm*64 + ty*4;
    const int col0 = bn*64 + tx*4;
#pragma unroll
    for (int i = 0; i < 4; ++i) {
#pragma unroll
        for (int jj = 0; jj < 4; ++jj) {
            const int row = row0 + i, col = col0 + jj;
            float v = acc[i][jj];
            if (col < 256) {
                if (row < N_DET) Abuf[(size_t)row*256 + col] = v;
                else             Bbuf[(size_t)(row - N_DET)*256 + col] = v;
            } else {
                const int o = col - 256;
                v += pb[o];
                if (row < N_DET) hnext[(size_t)row*256 + o] = fmaxf(v + tb[o], 0.f);
                else             phiT[(size_t)(row - N_DET)*256 + o] = v;
            }
        }
    }
}

// ---------------------------------------------------------------------------
// Masked column-max over dets + trk-row assembly:
//   colmax[m,o] = max_{n: aff[n,m]>0} Abuf[n,o]
//   hnext[512+m,o] = relu(phiT[m,o] + max(tb[o], colmax - Bbuf[m,o] + tb[o]))
// Block: 256 threads (one per o), 4 m's per block.
// ---------------------------------------------------------------------------
__global__ __launch_bounds__(256) void ec_colmax_kernel(
    const float* __restrict__ aff,
    const float* __restrict__ Abuf, const float* __restrict__ Bbuf,
    const float* __restrict__ phiT, const float* __restrict__ tb,
    float* __restrict__ hnext)
{
    const int o  = threadIdx.x;
    const int m0 = blockIdx.x * 4;
    float mx[4] = {-3.0e38f, -3.0e38f, -3.0e38f, -3.0e38f};
#pragma unroll 8
    for (int n = 0; n < 512; ++n) {
        const float a = Abuf[(size_t)n*256 + o];
#pragma unroll
        for (int mi = 0; mi < 4; ++mi) {
            if (aff[(size_t)n*512 + m0 + mi] > 0.f) mx[mi] = fmaxf(mx[mi], a);
        }
    }
    const float tbv = tb[o];
#pragma unroll
    for (int mi = 0; mi < 4; ++mi) {
        const int m = m0 + mi;
        const float v = fmaxf(tbv, mx[mi] - Bbuf[(size_t)m*256 + o] + tbv);
        hnext[(size_t)(N_DET + m)*256 + o] = fmaxf(phiT[(size_t)m*256 + o] + v, 0.f);
    }
}

// ---------------------------------------------------------------------------
// Head projection: P[1024][64] = h @ er_w1^T (raw; b1 folded into pairwise).
// 256 threads = 4 rows x 64 outs.
// ---------------------------------------------------------------------------
__global__ __launch_bounds__(256) void headp_kernel(
    const float* __restrict__ h, const float* __restrict__ w1, float* __restrict__ P)
{
    const int tid = threadIdx.x;
    const int o = tid & 63, rl = tid >> 6;
    const int row = blockIdx.x * 4 + rl;
    const float* hr = h + (size_t)row * 256;
    const float* wr = w1 + (size_t)o * 256;
    float s0 = 0.f, s1 = 0.f, s2 = 0.f, s3 = 0.f;
#pragma unroll
    for (int c = 0; c < 256; c += 4) {
        const float4 hv = *(const float4*)(hr + c);
        const float4 wv = *(const float4*)(wr + c);
        s0 = fmaf(hv.x, wv.x, s0);
        s1 = fmaf(hv.y, wv.y, s1);
        s2 = fmaf(hv.z, wv.z, s2);
        s3 = fmaf(hv.w, wv.w, s3);
    }
    P[(size_t)row * 64 + o] = (s0 + s1) + (s2 + s3);
}

// ---------------------------------------------------------------------------
// Pairwise affinity head:
//   e[o] = relu(Pt[m,o] - Pd[n,o] + b1[o]); s = e . w2 + b2; r = sigmoid(s)
//   out[n,m] = (aff*r == 0) ? 99 : aff*r
// Grid (2, 512): block handles one n x 256 m's.
// ---------------------------------------------------------------------------
__global__ __launch_bounds__(256) void pairwise_kernel(
    const float* __restrict__ P, const float* __restrict__ aff,
    const float* __restrict__ eb1, const float* __restrict__ ew2, const float* __restrict__ eb2,
    float* __restrict__ out)
{
    __shared__ float pd[64], sb1[64], sw2[64];
    const int n = blockIdx.y;
    const int t = threadIdx.x;
    if (t < 64)       pd[t]        = P[(size_t)n * 64 + t];
    else if (t < 128) sb1[t - 64]  = eb1[t - 64];
    else if (t < 192) sw2[t - 128] = ew2[t - 128];
    __syncthreads();
    const int m = blockIdx.x * 256 + t;
    const float* pt = P + (size_t)(N_DET + m) * 64;
    float s = eb2[0];
#pragma unroll
    for (int c = 0; c < 64; c += 4) {
        const float4 pv = *(const float4*)(pt + c);
        float e;
        e = fmaxf(pv.x - pd[c+0] + sb1[c+0], 0.f); s = fmaf(e, sw2[c+0], s);
        e = fmaxf(pv.y - pd[c+1] + sb1[c+1], 0.f); s = fmaf(e, sw2[c+1], s);
        e = fmaxf(pv.z - pd[c+2] + sb1[c+2], 0.f); s = fmaf(e, sw2[c+2], s);
        e = fmaxf(pv.w - pd[c+3] + sb1[c+3], 0.f); s = fmaf(e, sw2[c+3], s);
    }
    const float r = 1.f / (1.f + expf(-s));
    const float v = aff[(size_t)n * 512 + m] * r;
    out[(size_t)n * 512 + m] = (v == 0.f) ? 99.f : v;
}

// ---------------------------------------------------------------------------
extern "C" void kernel_launch(void* const* d_in, const int* in_sizes, int n_in,
                              void* d_out, int out_size, void* d_ws, size_t ws_size,
                              hipStream_t stream)
{
    (void)in_sizes; (void)n_in; (void)out_size; (void)ws_size;

    const float* det_pc  = (const float*)d_in[0];
    const float* det_box = (const float*)d_in[1];
    const float* trk_pc  = (const float*)d_in[2];
    const float* trk_box = (const float*)d_in[3];
    const float* aff     = (const float*)d_in[4];
    // d_in[5] = gt_affinity_matrix (unused by inference path)
    const float* pn_w1  = (const float*)d_in[6];
    const float* pn_b1  = (const float*)d_in[7];
    const float* pn_w2  = (const float*)d_in[8];
    const float* pn_b2  = (const float*)d_in[9];
    const float* pn_w3  = (const float*)d_in[10];
    const float* pn_b3  = (const float*)d_in[11];
    const float* mlp_w1 = (const float*)d_in[12];
    const float* mlp_b1 = (const float*)d_in[13];
    const float* mlp_w2 = (const float*)d_in[14];
    const float* mlp_b2 = (const float*)d_in[15];
    const float* l0_wih = (const float*)d_in[16];
    const float* l0_whh = (const float*)d_in[17];
    const float* l0_b   = (const float*)d_in[18];
    const float* l1_wih = (const float*)d_in[19];
    const float* l1_whh = (const float*)d_in[20];
    const float* l1_b   = (const float*)d_in[21];
    const float* ec_tw  = (const float*)d_in[22];
    const float* ec_tb  = (const float*)d_in[23];
    const float* ec_pw  = (const float*)d_in[24];
    const float* ec_pb  = (const float*)d_in[25];
    const float* er_w1  = (const float*)d_in[26];
    const float* er_b1  = (const float*)d_in[27];
    const float* er_w2  = (const float*)d_in[28];
    const float* er_b2  = (const float*)d_in[29];

    float* ws   = (float*)d_ws;
    float* hA   = ws;                    // [1024][256]
    float* hB   = hA + 1024*256;         // [1024][256]
    float* Abuf = hB + 1024*256;         // [512][256] theta(det)
    float* Bbuf = Abuf + 512*256;        // [512][256] theta(trk)
    float* phiT = Bbuf + 512*256;        // [512][256] phi(trk)+pb
    float* P    = phiT + 512*256;        // [1024][64]
    // total: 983040 floats = 3.93 MB

    pointnet_kernel<<<1024, 256, 0, stream>>>(det_pc, trk_pc, pn_w1, pn_b1, pn_w2, pn_b2,
                                              pn_w3, pn_b3, hA);
    detmlp_kernel<<<512, 128, 0, stream>>>(det_box, mlp_w1, mlp_b1, mlp_w2, mlp_b2, hA);
    lstm_kernel<<<128, 512, 0, stream>>>(trk_box, l0_wih, l0_whh, l0_b,
                                         l1_wih, l1_whh, l1_b, hA);

    float* hcur = hA;
    float* hnext = hB;
    for (int k = 0; k < 4; ++k) {
        const float* tw = ec_tw + (size_t)k * 256 * 256;
        const float* tb = ec_tb + (size_t)k * 256;
        const float* pw = ec_pw + (size_t)k * 256 * 256;
        const float* pb = ec_pb + (size_t)k * 256;
        ec_gemm_kernel<<<dim3(16, 8), 256, 0, stream>>>(hcur, tw, tb, pw, pb,
                                                        Abuf, Bbuf, phiT, hnext);
        ec_colmax_kernel<<<128, 256, 0, stream>>>(aff, Abuf, Bbuf, phiT, tb, hnext);
        float* tmp = hcur; hcur = hnext; hnext = tmp;
    }

    headp_kernel<<<256, 256, 0, stream>>>(hcur, er_w1, P);
    pairwise_kernel<<<dim3(2, 512), 256, 0, stream>>>(P, aff, er_b1, er_w2, er_b2,
                                                      (float*)d_out);
}

// Round 2
// 1284.667 us; speedup vs baseline: 3.2922x; 3.2922x over previous
//
#include <hip/hip_runtime.h>
#include <math.h>

#define N_DET 512
#define N_TRK 512
#define NPTS  256

__device__ __forceinline__ float sigm(float x) { return 1.f / (1.f + expf(-x)); }

// ---------------------------------------------------------------------------
// PointNet: per box (1024 boxes), 256 threads = 1 point each.
// ---------------------------------------------------------------------------
__global__ __launch_bounds__(256) void pointnet_kernel(
    const float* __restrict__ det_pc, const float* __restrict__ trk_pc,
    const float* __restrict__ w1, const float* __restrict__ b1,
    const float* __restrict__ w2, const float* __restrict__ b2,
    const float* __restrict__ w3, const float* __restrict__ b3,
    float* __restrict__ hout)
{
    const int box = blockIdx.x;
    const int p   = threadIdx.x;
    const float* pc = (box < N_DET) ? (det_pc + ((size_t)box * NPTS + p) * 3)
                                    : (trk_pc + ((size_t)(box - N_DET) * NPTS + p) * 3);
    const float x = pc[0], y = pc[1], z = pc[2];

    float h1[64];
#pragma unroll
    for (int o = 0; o < 64; ++o) {
        float s = b1[o];
        s = fmaf(w1[o*3+0], x, s);
        s = fmaf(w1[o*3+1], y, s);
        s = fmaf(w1[o*3+2], z, s);
        h1[o] = fmaxf(s, 0.f);
    }

    float h2[128];
#pragma unroll
    for (int o = 0; o < 128; ++o) {
        float a0 = 0.f, a1 = 0.f, a2 = 0.f, a3 = 0.f;
        const float* wr = w2 + o*64;
#pragma unroll
        for (int c = 0; c < 64; c += 4) {
            a0 = fmaf(wr[c+0], h1[c+0], a0);
            a1 = fmaf(wr[c+1], h1[c+1], a1);
            a2 = fmaf(wr[c+2], h1[c+2], a2);
            a3 = fmaf(wr[c+3], h1[c+3], a3);
        }
        h2[o] = fmaxf(b2[o] + ((a0+a1)+(a2+a3)), 0.f);
    }

    __shared__ float wmax[4][128];
    const int wave = threadIdx.x >> 6, lane = threadIdx.x & 63;
    for (int o = 0; o < 128; ++o) {
        float a0 = 0.f, a1 = 0.f, a2 = 0.f, a3 = 0.f;
        const float* wr = w3 + o*128;
#pragma unroll
        for (int c = 0; c < 128; c += 4) {
            a0 = fmaf(wr[c+0], h2[c+0], a0);
            a1 = fmaf(wr[c+1], h2[c+1], a1);
            a2 = fmaf(wr[c+2], h2[c+2], a2);
            a3 = fmaf(wr[c+3], h2[c+3], a3);
        }
        float s = fmaxf(b3[o] + ((a0+a1)+(a2+a3)), 0.f);
#pragma unroll
        for (int off = 32; off > 0; off >>= 1)
            s = fmaxf(s, __shfl_xor(s, off, 64));
        if (lane == 0) wmax[wave][o] = s;
    }
    __syncthreads();
    if (threadIdx.x < 128) {
        const int o = threadIdx.x;
        const float m = fmaxf(fmaxf(wmax[0][o], wmax[1][o]), fmaxf(wmax[2][o], wmax[3][o]));
        hout[(size_t)box * 256 + o] = m;
    }
}

// ---------------------------------------------------------------------------
// det motion MLP: 9 -> 64 (relu) -> 128. One block per det.
// ---------------------------------------------------------------------------
__global__ __launch_bounds__(128) void detmlp_kernel(
    const float* __restrict__ boxes,
    const float* __restrict__ w1, const float* __restrict__ b1,
    const float* __restrict__ w2, const float* __restrict__ b2,
    float* __restrict__ hout)
{
    __shared__ float xb[9];
    __shared__ float h1[64];
    const int b = blockIdx.x, t = threadIdx.x;
    if (t < 9) xb[t] = boxes[b*9 + t];
    __syncthreads();
    if (t < 64) {
        float s = b1[t];
#pragma unroll
        for (int c = 0; c < 9; ++c) s = fmaf(w1[t*9+c], xb[c], s);
        h1[t] = fmaxf(s, 0.f);
    }
    __syncthreads();
    float s = b2[t];
    const float* wr = w2 + t*64;
#pragma unroll
    for (int c = 0; c < 64; ++c) s = fmaf(wr[c], h1[c], s);
    hout[(size_t)b * 256 + 128 + t] = s;
}

// ---------------------------------------------------------------------------
// wih1T[k][r] = wih1[r][k]  (coalesced writes; reads L2-amortized)
// ---------------------------------------------------------------------------
__global__ __launch_bounds__(256) void transpose_wih1_kernel(
    const float* __restrict__ in, float* __restrict__ out)
{
    const int id = blockIdx.x * 256 + threadIdx.x;   // 65536 total
    const int k = id >> 9, r = id & 511;
    out[id] = in[r * 128 + k];
}

// ---------------------------------------------------------------------------
// LSTM layer 0, recurrent part. Thread t owns gate row t (whh0 row + wih0 row
// in registers, loaded ONCE). 4 batches per block, h-state in LDS [k][4b].
// Writes the full h0 sequence [512][10][128].
// ---------------------------------------------------------------------------
__global__ __launch_bounds__(512) void lstm_rec0_kernel(
    const float* __restrict__ xseq,   // [512][10][9]
    const float* __restrict__ wih0,   // [512][9]
    const float* __restrict__ whh0,   // [512][128]
    const float* __restrict__ b0,
    float* __restrict__ h0seq)        // [512][10][128]
{
    __shared__ float hs[128][4];      // h[k][b]
    __shared__ float xb[4][16];       // x_t per batch (9 used)
    __shared__ float gs[4][4][128];   // [b][gate][j]
    const int r  = threadIdx.x;
    const int q  = r >> 7, jj = r & 127;
    const int b4 = blockIdx.x * 4;
    const int mb = r >> 7, mj = r & 127;   // (batch, unit) this thread mixes

    float w[128];
#pragma unroll
    for (int k = 0; k < 128; k += 4) {
        const float4 v = *(const float4*)(whh0 + (size_t)r * 128 + k);
        w[k] = v.x; w[k+1] = v.y; w[k+2] = v.z; w[k+3] = v.w;
    }
    float wx[9];
#pragma unroll
    for (int c = 0; c < 9; ++c) wx[c] = wih0[(size_t)r * 9 + c];
    const float bias = b0[r];

    float cst = 0.f;
    hs[jj][q] = 0.f;
    __syncthreads();

    for (int t = 0; t < 10; ++t) {
        if (r < 64) {
            const int b = r >> 4, c = r & 15;
            if (c < 9) xb[b][c] = xseq[((size_t)(b4 + b) * 10 + t) * 9 + c];
        }
        __syncthreads();
        float a0 = bias, a1 = bias, a2 = bias, a3 = bias;
#pragma unroll
        for (int c = 0; c < 9; ++c) {
            a0 = fmaf(wx[c], xb[0][c], a0);
            a1 = fmaf(wx[c], xb[1][c], a1);
            a2 = fmaf(wx[c], xb[2][c], a2);
            a3 = fmaf(wx[c], xb[3][c], a3);
        }
#pragma unroll
        for (int k = 0; k < 128; ++k) {
            const float4 h4 = *(const float4*)&hs[k][0];
            a0 = fmaf(w[k], h4.x, a0);
            a1 = fmaf(w[k], h4.y, a1);
            a2 = fmaf(w[k], h4.z, a2);
            a3 = fmaf(w[k], h4.w, a3);
        }
        gs[0][q][jj] = a0;
        gs[1][q][jj] = a1;
        gs[2][q][jj] = a2;
        gs[3][q][jj] = a3;
        __syncthreads();   // hs reads done; gs complete
        const float gi = gs[mb][0][mj], gf = gs[mb][1][mj];
        const float gg = gs[mb][2][mj], go = gs[mb][3][mj];
        cst = sigm(gf) * cst + sigm(gi) * tanhf(gg);
        const float hn = sigm(go) * tanhf(cst);
        hs[mj][mb] = hn;
        h0seq[((size_t)(b4 + mb) * 10 + t) * 128 + mj] = hn;
        __syncthreads();   // hs ready for next step
    }
}

// ---------------------------------------------------------------------------
// LSTM layer 1, recurrent. whh1 row in registers; x-part weight streamed
// coalesced from wih1T (L2-resident). Outputs only final h -> hout col 128+.
// ---------------------------------------------------------------------------
__global__ __launch_bounds__(512) void lstm_rec1_kernel(
    const float* __restrict__ h0seq,  // [512][10][128]
    const float* __restrict__ wih1T,  // [128][512]
    const float* __restrict__ whh1,   // [512][128]
    const float* __restrict__ b1,
    float* __restrict__ hout)
{
    __shared__ float hs[128][4];      // h1 state [k][b]
    __shared__ float xs_[128][4];     // h0 input this step [k][b]
    __shared__ float gs[4][4][128];
    const int r  = threadIdx.x;
    const int q  = r >> 7, jj = r & 127;
    const int b4 = blockIdx.x * 4;
    const int mb = r >> 7, mj = r & 127;

    float w[128];
#pragma unroll
    for (int k = 0; k < 128; k += 4) {
        const float4 v = *(const float4*)(whh1 + (size_t)r * 128 + k);
        w[k] = v.x; w[k+1] = v.y; w[k+2] = v.z; w[k+3] = v.w;
    }
    const float bias = b1[r];

    float cst = 0.f;
    hs[jj][q] = 0.f;
    __syncthreads();

    for (int t = 0; t < 10; ++t) {
        {
            const int k = r & 127, b = r >> 7;
            xs_[k][b] = h0seq[((size_t)(b4 + b) * 10 + t) * 128 + k];
        }
        __syncthreads();
        float a0 = bias, a1 = bias, a2 = bias, a3 = bias;
#pragma unroll
        for (int k = 0; k < 128; ++k) {
            const float wxv = wih1T[k * 512 + r];
            const float4 x4 = *(const float4*)&xs_[k][0];
            const float4 h4 = *(const float4*)&hs[k][0];
            a0 = fmaf(wxv, x4.x, fmaf(w[k], h4.x, a0));
            a1 = fmaf(wxv, x4.y, fmaf(w[k], h4.y, a1));
            a2 = fmaf(wxv, x4.z, fmaf(w[k], h4.z, a2));
            a3 = fmaf(wxv, x4.w, fmaf(w[k], h4.w, a3));
        }
        gs[0][q][jj] = a0;
        gs[1][q][jj] = a1;
        gs[2][q][jj] = a2;
        gs[3][q][jj] = a3;
        __syncthreads();
        const float gi = gs[mb][0][mj], gf = gs[mb][1][mj];
        const float gg = gs[mb][2][mj], go = gs[mb][3][mj];
        cst = sigm(gf) * cst + sigm(gi) * tanhf(gg);
        const float hn = sigm(go) * tanhf(cst);
        hs[mj][mb] = hn;
        if (t == 9)
            hout[(size_t)(N_DET + b4 + mb) * 256 + 128 + mj] = hn;
        __syncthreads();
    }
}

// ---------------------------------------------------------------------------
// EdgeConv fused GEMM: C[1024][512] = h @ [tw;pw]^T with routing epilogue.
// ---------------------------------------------------------------------------
__global__ __launch_bounds__(256) void ec_gemm_kernel(
    const float* __restrict__ hin,
    const float* __restrict__ tw, const float* __restrict__ tb,
    const float* __restrict__ pw, const float* __restrict__ pb,
    float* __restrict__ Abuf, float* __restrict__ Bbuf,
    float* __restrict__ phiT, float* __restrict__ hnext)
{
    __shared__ float As[16][68];
    __shared__ float Ws[16][68];
    const int bm = blockIdx.x, bn = blockIdx.y;
    const int tid = threadIdx.x;
    const int tx = tid & 15, ty = tid >> 4;
    float acc[4][4] = {};
    for (int kk = 0; kk < 256; kk += 16) {
        if (kk) __syncthreads();
#pragma unroll
        for (int i = 0; i < 4; ++i) {
            const int e = tid + 256*i;
            const int r = e >> 4, c = e & 15;
            As[c][r] = hin[(size_t)(bm*64 + r)*256 + kk + c];
            const int n = bn*64 + r;
            const float* wp = (n < 256) ? (tw + (size_t)n*256) : (pw + (size_t)(n-256)*256);
            Ws[c][r] = wp[kk + c];
        }
        __syncthreads();
#pragma unroll
        for (int k = 0; k < 16; ++k) {
            const float4 a = *(const float4*)&As[k][ty*4];
            const float4 w = *(const float4*)&Ws[k][tx*4];
            const float av[4] = {a.x, a.y, a.z, a.w};
            const float wv[4] = {w.x, w.y, w.z, w.w};
#pragma unroll
            for (int i = 0; i < 4; ++i)
#pragma unroll
                for (int jj = 0; jj < 4; ++jj)
                    acc[i][jj] = fmaf(av[i], wv[jj], acc[i][jj]);
        }
    }
    const int row0 = bm*64 + ty*4;
    const int col0 = bn*64 + tx*4;
#pragma unroll
    for (int i = 0; i < 4; ++i) {
#pragma unroll
        for (int jj = 0; jj < 4; ++jj) {
            const int row = row0 + i, col = col0 + jj;
            float v = acc[i][jj];
            if (col < 256) {
                if (row < N_DET) Abuf[(size_t)row*256 + col] = v;
                else             Bbuf[(size_t)(row - N_DET)*256 + col] = v;
            } else {
                const int o = col - 256;
                v += pb[o];
                if (row < N_DET) hnext[(size_t)row*256 + o] = fmaxf(v + tb[o], 0.f);
                else             phiT[(size_t)(row - N_DET)*256 + o] = v;
            }
        }
    }
}

// ---------------------------------------------------------------------------
// Masked column-max over dets + trk-row assembly.
// ---------------------------------------------------------------------------
__global__ __launch_bounds__(256) void ec_colmax_kernel(
    const float* __restrict__ aff,
    const float* __restrict__ Abuf, const float* __restrict__ Bbuf,
    const float* __restrict__ phiT, const float* __restrict__ tb,
    float* __restrict__ hnext)
{
    const int o  = threadIdx.x;
    const int m0 = blockIdx.x * 4;
    float mx[4] = {-3.0e38f, -3.0e38f, -3.0e38f, -3.0e38f};
#pragma unroll 8
    for (int n = 0; n < 512; ++n) {
        const float a = Abuf[(size_t)n*256 + o];
#pragma unroll
        for (int mi = 0; mi < 4; ++mi) {
            if (aff[(size_t)n*512 + m0 + mi] > 0.f) mx[mi] = fmaxf(mx[mi], a);
        }
    }
    const float tbv = tb[o];
#pragma unroll
    for (int mi = 0; mi < 4; ++mi) {
        const int m = m0 + mi;
        const float v = fmaxf(tbv, mx[mi] - Bbuf[(size_t)m*256 + o] + tbv);
        hnext[(size_t)(N_DET + m)*256 + o] = fmaxf(phiT[(size_t)m*256 + o] + v, 0.f);
    }
}

// ---------------------------------------------------------------------------
// Head projection: P[1024][64] = h @ er_w1^T.
// ---------------------------------------------------------------------------
__global__ __launch_bounds__(256) void headp_kernel(
    const float* __restrict__ h, const float* __restrict__ w1, float* __restrict__ P)
{
    const int tid = threadIdx.x;
    const int o = tid & 63, rl = tid >> 6;
    const int row = blockIdx.x * 4 + rl;
    const float* hr = h + (size_t)row * 256;
    const float* wr = w1 + (size_t)o * 256;
    float s0 = 0.f, s1 = 0.f, s2 = 0.f, s3 = 0.f;
#pragma unroll
    for (int c = 0; c < 256; c += 4) {
        const float4 hv = *(const float4*)(hr + c);
        const float4 wv = *(const float4*)(wr + c);
        s0 = fmaf(hv.x, wv.x, s0);
        s1 = fmaf(hv.y, wv.y, s1);
        s2 = fmaf(hv.z, wv.z, s2);
        s3 = fmaf(hv.w, wv.w, s3);
    }
    P[(size_t)row * 64 + o] = (s0 + s1) + (s2 + s3);
}

// ---------------------------------------------------------------------------
// Pairwise affinity head.
// ---------------------------------------------------------------------------
__global__ __launch_bounds__(256) void pairwise_kernel(
    const float* __restrict__ P, const float* __restrict__ aff,
    const float* __restrict__ eb1, const float* __restrict__ ew2, const float* __restrict__ eb2,
    float* __restrict__ out)
{
    __shared__ float pd[64], sb1[64], sw2[64];
    const int n = blockIdx.y;
    const int t = threadIdx.x;
    if (t < 64)       pd[t]        = P[(size_t)n * 64 + t];
    else if (t < 128) sb1[t - 64]  = eb1[t - 64];
    else if (t < 192) sw2[t - 128] = ew2[t - 128];
    __syncthreads();
    const int m = blockIdx.x * 256 + t;
    const float* pt = P + (size_t)(N_DET + m) * 64;
    float s = eb2[0];
#pragma unroll
    for (int c = 0; c < 64; c += 4) {
        const float4 pv = *(const float4*)(pt + c);
        float e;
        e = fmaxf(pv.x - pd[c+0] + sb1[c+0], 0.f); s = fmaf(e, sw2[c+0], s);
        e = fmaxf(pv.y - pd[c+1] + sb1[c+1], 0.f); s = fmaf(e, sw2[c+1], s);
        e = fmaxf(pv.z - pd[c+2] + sb1[c+2], 0.f); s = fmaf(e, sw2[c+2], s);
        e = fmaxf(pv.w - pd[c+3] + sb1[c+3], 0.f); s = fmaf(e, sw2[c+3], s);
    }
    const float r = 1.f / (1.f + expf(-s));
    const float v = aff[(size_t)n * 512 + m] * r;
    out[(size_t)n * 512 + m] = (v == 0.f) ? 99.f : v;
}

// ---------------------------------------------------------------------------
extern "C" void kernel_launch(void* const* d_in, const int* in_sizes, int n_in,
                              void* d_out, int out_size, void* d_ws, size_t ws_size,
                              hipStream_t stream)
{
    (void)in_sizes; (void)n_in; (void)out_size; (void)ws_size;

    const float* det_pc  = (const float*)d_in[0];
    const float* det_box = (const float*)d_in[1];
    const float* trk_pc  = (const float*)d_in[2];
    const float* trk_box = (const float*)d_in[3];
    const float* aff     = (const float*)d_in[4];
    const float* pn_w1  = (const float*)d_in[6];
    const float* pn_b1  = (const float*)d_in[7];
    const float* pn_w2  = (const float*)d_in[8];
    const float* pn_b2  = (const float*)d_in[9];
    const float* pn_w3  = (const float*)d_in[10];
    const float* pn_b3  = (const float*)d_in[11];
    const float* mlp_w1 = (const float*)d_in[12];
    const float* mlp_b1 = (const float*)d_in[13];
    const float* mlp_w2 = (const float*)d_in[14];
    const float* mlp_b2 = (const float*)d_in[15];
    const float* l0_wih = (const float*)d_in[16];
    const float* l0_whh = (const float*)d_in[17];
    const float* l0_b   = (const float*)d_in[18];
    const float* l1_wih = (const float*)d_in[19];
    const float* l1_whh = (const float*)d_in[20];
    const float* l1_b   = (const float*)d_in[21];
    const float* ec_tw  = (const float*)d_in[22];
    const float* ec_tb  = (const float*)d_in[23];
    const float* ec_pw  = (const float*)d_in[24];
    const float* ec_pb  = (const float*)d_in[25];
    const float* er_w1  = (const float*)d_in[26];
    const float* er_b1  = (const float*)d_in[27];
    const float* er_w2  = (const float*)d_in[28];
    const float* er_b2  = (const float*)d_in[29];

    float* ws    = (float*)d_ws;
    float* hA    = ws;                    // [1024][256]
    float* hB    = hA + 1024*256;         // [1024][256]
    float* Abuf  = hB + 1024*256;         // [512][256]
    float* Bbuf  = Abuf + 512*256;        // [512][256]
    float* phiT  = Bbuf + 512*256;        // [512][256]
    float* P     = phiT + 512*256;        // [1024][64]
    float* h0seq = P + 1024*64;           // [512][10][128]
    float* wih1T = h0seq + 512*10*128;    // [128][512]
    // total ~6.6 MB

    pointnet_kernel<<<1024, 256, 0, stream>>>(det_pc, trk_pc, pn_w1, pn_b1, pn_w2, pn_b2,
                                              pn_w3, pn_b3, hA);
    detmlp_kernel<<<512, 128, 0, stream>>>(det_box, mlp_w1, mlp_b1, mlp_w2, mlp_b2, hA);
    transpose_wih1_kernel<<<256, 256, 0, stream>>>(l1_wih, wih1T);
    lstm_rec0_kernel<<<128, 512, 0, stream>>>(trk_box, l0_wih, l0_whh, l0_b, h0seq);
    lstm_rec1_kernel<<<128, 512, 0, stream>>>(h0seq, wih1T, l1_whh, l1_b, hA);

    float* hcur = hA;
    float* hnext = hB;
    for (int k = 0; k < 4; ++k) {
        const float* tw = ec_tw + (size_t)k * 256 * 256;
        const float* tb = ec_tb + (size_t)k * 256;
        const float* pw = ec_pw + (size_t)k * 256 * 256;
        const float* pb = ec_pb + (size_t)k * 256;
        ec_gemm_kernel<<<dim3(16, 8), 256, 0, stream>>>(hcur, tw, tb, pw, pb,
                                                        Abuf, Bbuf, phiT, hnext);
        ec_colmax_kernel<<<128, 256, 0, stream>>>(aff, Abuf, Bbuf, phiT, tb, hnext);
        float* tmp = hcur; hcur = hnext; hnext = tmp;
    }

    headp_kernel<<<256, 256, 0, stream>>>(hcur, er_w1, P);
    pairwise_kernel<<<dim3(2, 512), 256, 0, stream>>>(P, aff, er_b1, er_w2, er_b2,
                                                      (float*)d_out);
}

// Round 3
// 1110.852 us; speedup vs baseline: 3.8073x; 1.1565x over previous
//
#include <hip/hip_runtime.h>
#include <math.h>

#define N_DET 512
#define N_TRK 512
#define NPTS  256

typedef __attribute__((ext_vector_type(8))) short short8;
typedef __attribute__((ext_vector_type(4))) float f32x4;

__device__ __forceinline__ float sigm(float x) { return 1.f / (1.f + expf(-x)); }

__device__ __forceinline__ unsigned short f2bf(float f) {
    unsigned u = __float_as_uint(f);
    u += 0x7FFF + ((u >> 16) & 1);          // round-to-nearest-even
    return (unsigned short)(u >> 16);
}

// ---------------------------------------------------------------------------
// Pack pointnet w2/w3 into MFMA B-fragment-major bf16:
//   frag f (0..15: layer2, s=f>>3,n=f&7; 16..47: layer3, s,n of f-16)
//   lane l holds 8 bf16 = W[n*16 + (l&15)][s*32 + (l>>4)*8 + j]
// ---------------------------------------------------------------------------
__global__ __launch_bounds__(64) void pn_wprep_kernel(
    const float* __restrict__ w2, const float* __restrict__ w3,
    unsigned short* __restrict__ wfrag)
{
    const int f = blockIdx.x;          // 48
    const int lane = threadIdx.x;      // 64
    const int lm = lane & 15, lg = lane >> 4;
    const float* src;
    if (f < 16) {
        const int s = f >> 3, n = f & 7;
        src = w2 + (size_t)(n*16 + lm)*64 + s*32 + lg*8;
    } else {
        const int f2 = f - 16, s = f2 >> 3, n = f2 & 7;
        src = w3 + (size_t)(n*16 + lm)*128 + s*32 + lg*8;
    }
    short8 v;
#pragma unroll
    for (int j = 0; j < 8; ++j) v[j] = (short)f2bf(src[j]);
    *reinterpret_cast<short8*>(wfrag + ((size_t)f*64 + lane)*8) = v;
}

// ---------------------------------------------------------------------------
// PointNet fused MFMA kernel: one box per block, 256 threads (4 waves).
// L1 (3->64) fp32 per-thread -> bf16 h1 in LDS [256][72]
// L2 (64->128) MFMA, relu+bias -> bf16 h2 in LDS [256][136]
// L3 (128->128) MFMA -> maxpool over points -> hout[box][0:128]
// All M-tiles are wave-local (wave w owns points 64w..64w+63).
// ---------------------------------------------------------------------------
__global__ __launch_bounds__(256, 1) void pointnet_mfma_kernel(
    const float* __restrict__ det_pc, const float* __restrict__ trk_pc,
    const float* __restrict__ w1, const float* __restrict__ b1,
    const unsigned short* __restrict__ wfrag,
    const float* __restrict__ b2, const float* __restrict__ b3,
    float* __restrict__ hout)
{
    __shared__ unsigned short h1s[256*72];
    __shared__ unsigned short h2s[256*136];
    __shared__ float wmaxs[4][128];

    const int tid = threadIdx.x;
    const int box = blockIdx.x;
    const int lane = tid & 63, w = tid >> 6;
    const int lm = lane & 15, lg = lane >> 4;

    // ---- L1: thread = point ----
    const float* pc = (box < N_DET) ? det_pc + ((size_t)box*NPTS + tid)*3
                                    : trk_pc + ((size_t)(box - N_DET)*NPTS + tid)*3;
    const float x = pc[0], y = pc[1], z = pc[2];
#pragma unroll
    for (int j = 0; j < 8; ++j) {
        short8 v;
#pragma unroll
        for (int o = 0; o < 8; ++o) {
            const int ch = j*8 + o;
            float s = fmaf(w1[ch*3+0], x, fmaf(w1[ch*3+1], y,
                        fmaf(w1[ch*3+2], z, b1[ch])));
            v[o] = (short)f2bf(fmaxf(s, 0.f));
        }
        *reinterpret_cast<short8*>(&h1s[tid*72 + j*8]) = v;
    }
    __syncthreads();

    // ---- L2: [64 pts x 64] @ w2^T -> h2, per wave 4 M-tiles x 8 N-tiles ----
    short8 w2f[16];
#pragma unroll
    for (int f = 0; f < 16; ++f)
        w2f[f] = *reinterpret_cast<const short8*>(wfrag + ((size_t)f*64 + lane)*8);
    float b2v[8];
#pragma unroll
    for (int n = 0; n < 8; ++n) b2v[n] = b2[n*16 + lm];

#pragma unroll
    for (int t = 0; t < 4; ++t) {
        const int arow = w*64 + t*16 + lm;
        const short8 a0 = *reinterpret_cast<const short8*>(&h1s[arow*72 + lg*8]);
        const short8 a1 = *reinterpret_cast<const short8*>(&h1s[arow*72 + 32 + lg*8]);
        const int wrow = w*64 + t*16 + lg*4;
#pragma unroll
        for (int n = 0; n < 8; ++n) {
            f32x4 acc = {0.f, 0.f, 0.f, 0.f};
            acc = __builtin_amdgcn_mfma_f32_16x16x32_bf16(a0, w2f[n],     acc, 0, 0, 0);
            acc = __builtin_amdgcn_mfma_f32_16x16x32_bf16(a1, w2f[8 + n], acc, 0, 0, 0);
#pragma unroll
            for (int r = 0; r < 4; ++r) {
                const float v = fmaxf(acc[r] + b2v[n], 0.f);
                h2s[(wrow + r)*136 + n*16 + lm] = f2bf(v);
            }
        }
    }
    __syncthreads();

    // ---- L3: [64 pts x 128] @ w3^T, fused maxpool ----
    short8 w3f[32];
#pragma unroll
    for (int f = 0; f < 32; ++f)
        w3f[f] = *reinterpret_cast<const short8*>(wfrag + ((size_t)(16 + f)*64 + lane)*8);

    float pm[8];
#pragma unroll
    for (int n = 0; n < 8; ++n) pm[n] = -3.0e38f;

#pragma unroll
    for (int t = 0; t < 4; ++t) {
        const int arow = w*64 + t*16 + lm;
        const short8 a0 = *reinterpret_cast<const short8*>(&h2s[arow*136 +  0 + lg*8]);
        const short8 a1 = *reinterpret_cast<const short8*>(&h2s[arow*136 + 32 + lg*8]);
        const short8 a2 = *reinterpret_cast<const short8*>(&h2s[arow*136 + 64 + lg*8]);
        const short8 a3 = *reinterpret_cast<const short8*>(&h2s[arow*136 + 96 + lg*8]);
#pragma unroll
        for (int n = 0; n < 8; ++n) {
            f32x4 acc = {0.f, 0.f, 0.f, 0.f};
            acc = __builtin_amdgcn_mfma_f32_16x16x32_bf16(a0, w3f[n],      acc, 0, 0, 0);
            acc = __builtin_amdgcn_mfma_f32_16x16x32_bf16(a1, w3f[8 + n],  acc, 0, 0, 0);
            acc = __builtin_amdgcn_mfma_f32_16x16x32_bf16(a2, w3f[16 + n], acc, 0, 0, 0);
            acc = __builtin_amdgcn_mfma_f32_16x16x32_bf16(a3, w3f[24 + n], acc, 0, 0, 0);
#pragma unroll
            for (int r = 0; r < 4; ++r) pm[n] = fmaxf(pm[n], acc[r]);
        }
    }
#pragma unroll
    for (int n = 0; n < 8; ++n) {
        float v = pm[n];
        v = fmaxf(v, __shfl_xor(v, 16, 64));
        v = fmaxf(v, __shfl_xor(v, 32, 64));
        pm[n] = v;
    }
    if (lg == 0) {
#pragma unroll
        for (int n = 0; n < 8; ++n) wmaxs[w][n*16 + lm] = pm[n];
    }
    __syncthreads();
    if (tid < 128) {
        const float m = fmaxf(fmaxf(wmaxs[0][tid], wmaxs[1][tid]),
                              fmaxf(wmaxs[2][tid], wmaxs[3][tid]));
        hout[(size_t)box*256 + tid] = fmaxf(m + b3[tid], 0.f);
    }
}

// ---------------------------------------------------------------------------
// det motion MLP: 9 -> 64 (relu) -> 128. One block per det.
// ---------------------------------------------------------------------------
__global__ __launch_bounds__(128) void detmlp_kernel(
    const float* __restrict__ boxes,
    const float* __restrict__ w1, const float* __restrict__ b1,
    const float* __restrict__ w2, const float* __restrict__ b2,
    float* __restrict__ hout)
{
    __shared__ float xb[9];
    __shared__ float h1[64];
    const int b = blockIdx.x, t = threadIdx.x;
    if (t < 9) xb[t] = boxes[b*9 + t];
    __syncthreads();
    if (t < 64) {
        float s = b1[t];
#pragma unroll
        for (int c = 0; c < 9; ++c) s = fmaf(w1[t*9+c], xb[c], s);
        h1[t] = fmaxf(s, 0.f);
    }
    __syncthreads();
    float s = b2[t];
    const float* wr = w2 + t*64;
#pragma unroll
    for (int c = 0; c < 64; ++c) s = fmaf(wr[c], h1[c], s);
    hout[(size_t)b * 256 + 128 + t] = s;
}

// ---------------------------------------------------------------------------
__global__ __launch_bounds__(256) void transpose_wih1_kernel(
    const float* __restrict__ in, float* __restrict__ out)
{
    const int id = blockIdx.x * 256 + threadIdx.x;   // 65536 total
    const int k = id >> 9, r = id & 511;
    out[id] = in[r * 128 + k];
}

// ---------------------------------------------------------------------------
// LSTM layer 0, weights-in-registers recurrent kernel.
// ---------------------------------------------------------------------------
__global__ __launch_bounds__(512) void lstm_rec0_kernel(
    const float* __restrict__ xseq,
    const float* __restrict__ wih0, const float* __restrict__ whh0,
    const float* __restrict__ b0, float* __restrict__ h0seq)
{
    __shared__ float hs[128][4];
    __shared__ float xb[4][16];
    __shared__ float gs[4][4][128];
    const int r  = threadIdx.x;
    const int q  = r >> 7, jj = r & 127;
    const int b4 = blockIdx.x * 4;
    const int mb = r >> 7, mj = r & 127;

    float w[128];
#pragma unroll
    for (int k = 0; k < 128; k += 4) {
        const float4 v = *(const float4*)(whh0 + (size_t)r * 128 + k);
        w[k] = v.x; w[k+1] = v.y; w[k+2] = v.z; w[k+3] = v.w;
    }
    float wx[9];
#pragma unroll
    for (int c = 0; c < 9; ++c) wx[c] = wih0[(size_t)r * 9 + c];
    const float bias = b0[r];

    float cst = 0.f;
    hs[jj][q] = 0.f;
    __syncthreads();

    for (int t = 0; t < 10; ++t) {
        if (r < 64) {
            const int b = r >> 4, c = r & 15;
            if (c < 9) xb[b][c] = xseq[((size_t)(b4 + b) * 10 + t) * 9 + c];
        }
        __syncthreads();
        float a0 = bias, a1 = bias, a2 = bias, a3 = bias;
#pragma unroll
        for (int c = 0; c < 9; ++c) {
            a0 = fmaf(wx[c], xb[0][c], a0);
            a1 = fmaf(wx[c], xb[1][c], a1);
            a2 = fmaf(wx[c], xb[2][c], a2);
            a3 = fmaf(wx[c], xb[3][c], a3);
        }
#pragma unroll
        for (int k = 0; k < 128; ++k) {
            const float4 h4 = *(const float4*)&hs[k][0];
            a0 = fmaf(w[k], h4.x, a0);
            a1 = fmaf(w[k], h4.y, a1);
            a2 = fmaf(w[k], h4.z, a2);
            a3 = fmaf(w[k], h4.w, a3);
        }
        gs[0][q][jj] = a0;
        gs[1][q][jj] = a1;
        gs[2][q][jj] = a2;
        gs[3][q][jj] = a3;
        __syncthreads();
        const float gi = gs[mb][0][mj], gf = gs[mb][1][mj];
        const float gg = gs[mb][2][mj], go = gs[mb][3][mj];
        cst = sigm(gf) * cst + sigm(gi) * tanhf(gg);
        const float hn = sigm(go) * tanhf(cst);
        hs[mj][mb] = hn;
        h0seq[((size_t)(b4 + mb) * 10 + t) * 128 + mj] = hn;
        __syncthreads();
    }
}

// ---------------------------------------------------------------------------
// LSTM layer 1.
// ---------------------------------------------------------------------------
__global__ __launch_bounds__(512) void lstm_rec1_kernel(
    const float* __restrict__ h0seq, const float* __restrict__ wih1T,
    const float* __restrict__ whh1, const float* __restrict__ b1,
    float* __restrict__ hout)
{
    __shared__ float hs[128][4];
    __shared__ float xs_[128][4];
    __shared__ float gs[4][4][128];
    const int r  = threadIdx.x;
    const int q  = r >> 7, jj = r & 127;
    const int b4 = blockIdx.x * 4;
    const int mb = r >> 7, mj = r & 127;

    float w[128];
#pragma unroll
    for (int k = 0; k < 128; k += 4) {
        const float4 v = *(const float4*)(whh1 + (size_t)r * 128 + k);
        w[k] = v.x; w[k+1] = v.y; w[k+2] = v.z; w[k+3] = v.w;
    }
    const float bias = b1[r];

    float cst = 0.f;
    hs[jj][q] = 0.f;
    __syncthreads();

    for (int t = 0; t < 10; ++t) {
        {
            const int k = r & 127, b = r >> 7;
            xs_[k][b] = h0seq[((size_t)(b4 + b) * 10 + t) * 128 + k];
        }
        __syncthreads();
        float a0 = bias, a1 = bias, a2 = bias, a3 = bias;
#pragma unroll
        for (int k = 0; k < 128; ++k) {
            const float wxv = wih1T[k * 512 + r];
            const float4 x4 = *(const float4*)&xs_[k][0];
            const float4 h4 = *(const float4*)&hs[k][0];
            a0 = fmaf(wxv, x4.x, fmaf(w[k], h4.x, a0));
            a1 = fmaf(wxv, x4.y, fmaf(w[k], h4.y, a1));
            a2 = fmaf(wxv, x4.z, fmaf(w[k], h4.z, a2));
            a3 = fmaf(wxv, x4.w, fmaf(w[k], h4.w, a3));
        }
        gs[0][q][jj] = a0;
        gs[1][q][jj] = a1;
        gs[2][q][jj] = a2;
        gs[3][q][jj] = a3;
        __syncthreads();
        const float gi = gs[mb][0][mj], gf = gs[mb][1][mj];
        const float gg = gs[mb][2][mj], go = gs[mb][3][mj];
        cst = sigm(gf) * cst + sigm(gi) * tanhf(gg);
        const float hn = sigm(go) * tanhf(cst);
        hs[mj][mb] = hn;
        if (t == 9)
            hout[(size_t)(N_DET + b4 + mb) * 256 + 128 + mj] = hn;
        __syncthreads();
    }
}

// ---------------------------------------------------------------------------
// EdgeConv fused GEMM: C[1024][512] = h @ [tw;pw]^T with routing epilogue.
// ---------------------------------------------------------------------------
__global__ __launch_bounds__(256) void ec_gemm_kernel(
    const float* __restrict__ hin,
    const float* __restrict__ tw, const float* __restrict__ tb,
    const float* __restrict__ pw, const float* __restrict__ pb,
    float* __restrict__ Abuf, float* __restrict__ Bbuf,
    float* __restrict__ phiT, float* __restrict__ hnext)
{
    __shared__ float As[16][68];
    __shared__ float Ws[16][68];
    const int bm = blockIdx.x, bn = blockIdx.y;
    const int tid = threadIdx.x;
    const int tx = tid & 15, ty = tid >> 4;
    float acc[4][4] = {};
    for (int kk = 0; kk < 256; kk += 16) {
        if (kk) __syncthreads();
#pragma unroll
        for (int i = 0; i < 4; ++i) {
            const int e = tid + 256*i;
            const int r = e >> 4, c = e & 15;
            As[c][r] = hin[(size_t)(bm*64 + r)*256 + kk + c];
            const int n = bn*64 + r;
            const float* wp = (n < 256) ? (tw + (size_t)n*256) : (pw + (size_t)(n-256)*256);
            Ws[c][r] = wp[kk + c];
        }
        __syncthreads();
#pragma unroll
        for (int k = 0; k < 16; ++k) {
            const float4 a = *(const float4*)&As[k][ty*4];
            const float4 w = *(const float4*)&Ws[k][tx*4];
            const float av[4] = {a.x, a.y, a.z, a.w};
            const float wv[4] = {w.x, w.y, w.z, w.w};
#pragma unroll
            for (int i = 0; i < 4; ++i)
#pragma unroll
                for (int jj = 0; jj < 4; ++jj)
                    acc[i][jj] = fmaf(av[i], wv[jj], acc[i][jj]);
        }
    }
    const int row0 = bm*64 + ty*4;
    const int col0 = bn*64 + tx*4;
#pragma unroll
    for (int i = 0; i < 4; ++i) {
#pragma unroll
        for (int jj = 0; jj < 4; ++jj) {
            const int row = row0 + i, col = col0 + jj;
            float v = acc[i][jj];
            if (col < 256) {
                if (row < N_DET) Abuf[(size_t)row*256 + col] = v;
                else             Bbuf[(size_t)(row - N_DET)*256 + col] = v;
            } else {
                const int o = col - 256;
                v += pb[o];
                if (row < N_DET) hnext[(size_t)row*256 + o] = fmaxf(v + tb[o], 0.f);
                else             phiT[(size_t)(row - N_DET)*256 + o] = v;
            }
        }
    }
}

// ---------------------------------------------------------------------------
// Masked column-max, one m per block (512 blocks): wave-uniform aff loads.
// ---------------------------------------------------------------------------
__global__ __launch_bounds__(256) void ec_colmax_kernel(
    const float* __restrict__ aff,
    const float* __restrict__ Abuf, const float* __restrict__ Bbuf,
    const float* __restrict__ phiT, const float* __restrict__ tb,
    float* __restrict__ hnext)
{
    const int o = threadIdx.x;
    const int m = blockIdx.x;
    float mx = -3.0e38f;
#pragma unroll 4
    for (int n = 0; n < 512; ++n) {
        const float a = Abuf[(size_t)n*256 + o];
        if (aff[(size_t)n*512 + m] > 0.f) mx = fmaxf(mx, a);
    }
    const float tbv = tb[o];
    const float v = fmaxf(tbv, mx - Bbuf[(size_t)m*256 + o] + tbv);
    hnext[(size_t)(N_DET + m)*256 + o] = fmaxf(phiT[(size_t)m*256 + o] + v, 0.f);
}

// ---------------------------------------------------------------------------
// Head projection: P[1024][64] = h @ er_w1^T.
// ---------------------------------------------------------------------------
__global__ __launch_bounds__(256) void headp_kernel(
    const float* __restrict__ h, const float* __restrict__ w1, float* __restrict__ P)
{
    const int tid = threadIdx.x;
    const int o = tid & 63, rl = tid >> 6;
    const int row = blockIdx.x * 4 + rl;
    const float* hr = h + (size_t)row * 256;
    const float* wr = w1 + (size_t)o * 256;
    float s0 = 0.f, s1 = 0.f, s2 = 0.f, s3 = 0.f;
#pragma unroll
    for (int c = 0; c < 256; c += 4) {
        const float4 hv = *(const float4*)(hr + c);
        const float4 wv = *(const float4*)(wr + c);
        s0 = fmaf(hv.x, wv.x, s0);
        s1 = fmaf(hv.y, wv.y, s1);
        s2 = fmaf(hv.z, wv.z, s2);
        s3 = fmaf(hv.w, wv.w, s3);
    }
    P[(size_t)row * 64 + o] = (s0 + s1) + (s2 + s3);
}

// ---------------------------------------------------------------------------
// Pairwise affinity head.
// ---------------------------------------------------------------------------
__global__ __launch_bounds__(256) void pairwise_kernel(
    const float* __restrict__ P, const float* __restrict__ aff,
    const float* __restrict__ eb1, const float* __restrict__ ew2, const float* __restrict__ eb2,
    float* __restrict__ out)
{
    __shared__ float pd[64], sb1[64], sw2[64];
    const int n = blockIdx.y;
    const int t = threadIdx.x;
    if (t < 64)       pd[t]        = P[(size_t)n * 64 + t];
    else if (t < 128) sb1[t - 64]  = eb1[t - 64];
    else if (t < 192) sw2[t - 128] = ew2[t - 128];
    __syncthreads();
    const int m = blockIdx.x * 256 + t;
    const float* pt = P + (size_t)(N_DET + m) * 64;
    float s = eb2[0];
#pragma unroll
    for (int c = 0; c < 64; c += 4) {
        const float4 pv = *(const float4*)(pt + c);
        float e;
        e = fmaxf(pv.x - pd[c+0] + sb1[c+0], 0.f); s = fmaf(e, sw2[c+0], s);
        e = fmaxf(pv.y - pd[c+1] + sb1[c+1], 0.f); s = fmaf(e, sw2[c+1], s);
        e = fmaxf(pv.z - pd[c+2] + sb1[c+2], 0.f); s = fmaf(e, sw2[c+2], s);
        e = fmaxf(pv.w - pd[c+3] + sb1[c+3], 0.f); s = fmaf(e, sw2[c+3], s);
    }
    const float r = 1.f / (1.f + expf(-s));
    const float v = aff[(size_t)n * 512 + m] * r;
    out[(size_t)n * 512 + m] = (v == 0.f) ? 99.f : v;
}

// ---------------------------------------------------------------------------
extern "C" void kernel_launch(void* const* d_in, const int* in_sizes, int n_in,
                              void* d_out, int out_size, void* d_ws, size_t ws_size,
                              hipStream_t stream)
{
    (void)in_sizes; (void)n_in; (void)out_size; (void)ws_size;

    const float* det_pc  = (const float*)d_in[0];
    const float* det_box = (const float*)d_in[1];
    const float* trk_pc  = (const float*)d_in[2];
    const float* trk_box = (const float*)d_in[3];
    const float* aff     = (const float*)d_in[4];
    const float* pn_w1  = (const float*)d_in[6];
    const float* pn_b1  = (const float*)d_in[7];
    const float* pn_w2  = (const float*)d_in[8];
    const float* pn_b2  = (const float*)d_in[9];
    const float* pn_w3  = (const float*)d_in[10];
    const float* pn_b3  = (const float*)d_in[11];
    const float* mlp_w1 = (const float*)d_in[12];
    const float* mlp_b1 = (const float*)d_in[13];
    const float* mlp_w2 = (const float*)d_in[14];
    const float* mlp_b2 = (const float*)d_in[15];
    const float* l0_wih = (const float*)d_in[16];
    const float* l0_whh = (const float*)d_in[17];
    const float* l0_b   = (const float*)d_in[18];
    const float* l1_wih = (const float*)d_in[19];
    const float* l1_whh = (const float*)d_in[20];
    const float* l1_b   = (const float*)d_in[21];
    const float* ec_tw  = (const float*)d_in[22];
    const float* ec_tb  = (const float*)d_in[23];
    const float* ec_pw  = (const float*)d_in[24];
    const float* ec_pb  = (const float*)d_in[25];
    const float* er_w1  = (const float*)d_in[26];
    const float* er_b1  = (const float*)d_in[27];
    const float* er_w2  = (const float*)d_in[28];
    const float* er_b2  = (const float*)d_in[29];

    float* ws    = (float*)d_ws;
    float* hA    = ws;                    // [1024][256]
    float* hB    = hA + 1024*256;         // [1024][256]
    float* Abuf  = hB + 1024*256;         // [512][256]
    float* Bbuf  = Abuf + 512*256;        // [512][256]
    float* phiT  = Bbuf + 512*256;        // [512][256]
    float* P     = phiT + 512*256;        // [1024][64]
    float* h0seq = P + 1024*64;           // [512][10][128]
    float* wih1T = h0seq + 512*10*128;    // [128][512]
    unsigned short* wfrag = (unsigned short*)(wih1T + 128*512);  // 48*64*8 bf16

    pn_wprep_kernel<<<48, 64, 0, stream>>>(pn_w2, pn_w3, wfrag);
    pointnet_mfma_kernel<<<1024, 256, 0, stream>>>(det_pc, trk_pc, pn_w1, pn_b1,
                                                   wfrag, pn_b2, pn_b3, hA);
    detmlp_kernel<<<512, 128, 0, stream>>>(det_box, mlp_w1, mlp_b1, mlp_w2, mlp_b2, hA);
    transpose_wih1_kernel<<<256, 256, 0, stream>>>(l1_wih, wih1T);
    lstm_rec0_kernel<<<128, 512, 0, stream>>>(trk_box, l0_wih, l0_whh, l0_b, h0seq);
    lstm_rec1_kernel<<<128, 512, 0, stream>>>(h0seq, wih1T, l1_whh, l1_b, hA);

    float* hcur = hA;
    float* hnext = hB;
    for (int k = 0; k < 4; ++k) {
        const float* tw = ec_tw + (size_t)k * 256 * 256;
        const float* tb = ec_tb + (size_t)k * 256;
        const float* pw = ec_pw + (size_t)k * 256 * 256;
        const float* pb = ec_pb + (size_t)k * 256;
        ec_gemm_kernel<<<dim3(16, 8), 256, 0, stream>>>(hcur, tw, tb, pw, pb,
                                                        Abuf, Bbuf, phiT, hnext);
        ec_colmax_kernel<<<512, 256, 0, stream>>>(aff, Abuf, Bbuf, phiT, tb, hnext);
        float* tmp = hcur; hcur = hnext; hnext = tmp;
    }

    headp_kernel<<<256, 256, 0, stream>>>(hcur, er_w1, P);
    pairwise_kernel<<<dim3(2, 512), 256, 0, stream>>>(P, aff, er_b1, er_w2, er_b2,
                                                      (float*)d_out);
}

// Round 4
// 486.777 us; speedup vs baseline: 8.6885x; 2.2821x over previous
//
#include <hip/hip_runtime.h>
#include <math.h>

#define N_DET 512
#define N_TRK 512
#define NPTS  256

typedef __attribute__((ext_vector_type(8))) short short8;
typedef __attribute__((ext_vector_type(4))) float f32x4;

__device__ __forceinline__ float sigm(float x) { return 1.f / (1.f + expf(-x)); }

__device__ __forceinline__ unsigned short f2bf(float f) {
    unsigned u = __float_as_uint(f);
    u += 0x7FFF + ((u >> 16) & 1);          // round-to-nearest-even
    return (unsigned short)(u >> 16);
}

// ---------------------------------------------------------------------------
// Pack pointnet w2/w3 into MFMA B-fragment-major bf16.
// ---------------------------------------------------------------------------
__global__ __launch_bounds__(64) void pn_wprep_kernel(
    const float* __restrict__ w2, const float* __restrict__ w3,
    unsigned short* __restrict__ wfrag)
{
    const int f = blockIdx.x;          // 48
    const int lane = threadIdx.x;      // 64
    const int lm = lane & 15, lg = lane >> 4;
    const float* src;
    if (f < 16) {
        const int s = f >> 3, n = f & 7;
        src = w2 + (size_t)(n*16 + lm)*64 + s*32 + lg*8;
    } else {
        const int f2 = f - 16, s = f2 >> 3, n = f2 & 7;
        src = w3 + (size_t)(n*16 + lm)*128 + s*32 + lg*8;
    }
    short8 v;
#pragma unroll
    for (int j = 0; j < 8; ++j) v[j] = (short)f2bf(src[j]);
    *reinterpret_cast<short8*>(wfrag + ((size_t)f*64 + lane)*8) = v;
}

// ---------------------------------------------------------------------------
// PointNet fused MFMA kernel: one box per block, 256 threads (4 waves).
// ---------------------------------------------------------------------------
__global__ __launch_bounds__(256, 1) void pointnet_mfma_kernel(
    const float* __restrict__ det_pc, const float* __restrict__ trk_pc,
    const float* __restrict__ w1, const float* __restrict__ b1,
    const unsigned short* __restrict__ wfrag,
    const float* __restrict__ b2, const float* __restrict__ b3,
    float* __restrict__ hout)
{
    __shared__ unsigned short h1s[256*72];
    __shared__ unsigned short h2s[256*136];
    __shared__ float wmaxs[4][128];

    const int tid = threadIdx.x;
    const int box = blockIdx.x;
    const int lane = tid & 63, w = tid >> 6;
    const int lm = lane & 15, lg = lane >> 4;

    // ---- L1: thread = point ----
    const float* pc = (box < N_DET) ? det_pc + ((size_t)box*NPTS + tid)*3
                                    : trk_pc + ((size_t)(box - N_DET)*NPTS + tid)*3;
    const float x = pc[0], y = pc[1], z = pc[2];
#pragma unroll
    for (int j = 0; j < 8; ++j) {
        short8 v;
#pragma unroll
        for (int o = 0; o < 8; ++o) {
            const int ch = j*8 + o;
            float s = fmaf(w1[ch*3+0], x, fmaf(w1[ch*3+1], y,
                        fmaf(w1[ch*3+2], z, b1[ch])));
            v[o] = (short)f2bf(fmaxf(s, 0.f));
        }
        *reinterpret_cast<short8*>(&h1s[tid*72 + j*8]) = v;
    }
    __syncthreads();

    // ---- L2: [64 pts x 64] @ w2^T -> h2 ----
    short8 w2f[16];
#pragma unroll
    for (int f = 0; f < 16; ++f)
        w2f[f] = *reinterpret_cast<const short8*>(wfrag + ((size_t)f*64 + lane)*8);
    float b2v[8];
#pragma unroll
    for (int n = 0; n < 8; ++n) b2v[n] = b2[n*16 + lm];

#pragma unroll
    for (int t = 0; t < 4; ++t) {
        const int arow = w*64 + t*16 + lm;
        const short8 a0 = *reinterpret_cast<const short8*>(&h1s[arow*72 + lg*8]);
        const short8 a1 = *reinterpret_cast<const short8*>(&h1s[arow*72 + 32 + lg*8]);
        const int wrow = w*64 + t*16 + lg*4;
#pragma unroll
        for (int n = 0; n < 8; ++n) {
            f32x4 acc = {0.f, 0.f, 0.f, 0.f};
            acc = __builtin_amdgcn_mfma_f32_16x16x32_bf16(a0, w2f[n],     acc, 0, 0, 0);
            acc = __builtin_amdgcn_mfma_f32_16x16x32_bf16(a1, w2f[8 + n], acc, 0, 0, 0);
#pragma unroll
            for (int r = 0; r < 4; ++r) {
                const float v = fmaxf(acc[r] + b2v[n], 0.f);
                h2s[(wrow + r)*136 + n*16 + lm] = f2bf(v);
            }
        }
    }
    __syncthreads();

    // ---- L3: [64 pts x 128] @ w3^T, fused maxpool ----
    short8 w3f[32];
#pragma unroll
    for (int f = 0; f < 32; ++f)
        w3f[f] = *reinterpret_cast<const short8*>(wfrag + ((size_t)(16 + f)*64 + lane)*8);

    float pm[8];
#pragma unroll
    for (int n = 0; n < 8; ++n) pm[n] = -3.0e38f;

#pragma unroll
    for (int t = 0; t < 4; ++t) {
        const int arow = w*64 + t*16 + lm;
        const short8 a0 = *reinterpret_cast<const short8*>(&h2s[arow*136 +  0 + lg*8]);
        const short8 a1 = *reinterpret_cast<const short8*>(&h2s[arow*136 + 32 + lg*8]);
        const short8 a2 = *reinterpret_cast<const short8*>(&h2s[arow*136 + 64 + lg*8]);
        const short8 a3 = *reinterpret_cast<const short8*>(&h2s[arow*136 + 96 + lg*8]);
#pragma unroll
        for (int n = 0; n < 8; ++n) {
            f32x4 acc = {0.f, 0.f, 0.f, 0.f};
            acc = __builtin_amdgcn_mfma_f32_16x16x32_bf16(a0, w3f[n],      acc, 0, 0, 0);
            acc = __builtin_amdgcn_mfma_f32_16x16x32_bf16(a1, w3f[8 + n],  acc, 0, 0, 0);
            acc = __builtin_amdgcn_mfma_f32_16x16x32_bf16(a2, w3f[16 + n], acc, 0, 0, 0);
            acc = __builtin_amdgcn_mfma_f32_16x16x32_bf16(a3, w3f[24 + n], acc, 0, 0, 0);
#pragma unroll
            for (int r = 0; r < 4; ++r) pm[n] = fmaxf(pm[n], acc[r]);
        }
    }
#pragma unroll
    for (int n = 0; n < 8; ++n) {
        float v = pm[n];
        v = fmaxf(v, __shfl_xor(v, 16, 64));
        v = fmaxf(v, __shfl_xor(v, 32, 64));
        pm[n] = v;
    }
    if (lg == 0) {
#pragma unroll
        for (int n = 0; n < 8; ++n) wmaxs[w][n*16 + lm] = pm[n];
    }
    __syncthreads();
    if (tid < 128) {
        const float m = fmaxf(fmaxf(wmaxs[0][tid], wmaxs[1][tid]),
                              fmaxf(wmaxs[2][tid], wmaxs[3][tid]));
        hout[(size_t)box*256 + tid] = fmaxf(m + b3[tid], 0.f);
    }
}

// ---------------------------------------------------------------------------
// det motion MLP: 9 -> 64 (relu) -> 128. One block per det.
// ---------------------------------------------------------------------------
__global__ __launch_bounds__(128) void detmlp_kernel(
    const float* __restrict__ boxes,
    const float* __restrict__ w1, const float* __restrict__ b1,
    const float* __restrict__ w2, const float* __restrict__ b2,
    float* __restrict__ hout)
{
    __shared__ float xb[9];
    __shared__ float h1[64];
    const int b = blockIdx.x, t = threadIdx.x;
    if (t < 9) xb[t] = boxes[b*9 + t];
    __syncthreads();
    if (t < 64) {
        float s = b1[t];
#pragma unroll
        for (int c = 0; c < 9; ++c) s = fmaf(w1[t*9+c], xb[c], s);
        h1[t] = fmaxf(s, 0.f);
    }
    __syncthreads();
    float s = b2[t];
    const float* wr = w2 + t*64;
#pragma unroll
    for (int c = 0; c < 64; ++c) s = fmaf(wr[c], h1[c], s);
    hout[(size_t)b * 256 + 128 + t] = s;
}

// ---------------------------------------------------------------------------
__global__ __launch_bounds__(256) void transpose_wih1_kernel(
    const float* __restrict__ in, float* __restrict__ out)
{
    const int id = blockIdx.x * 256 + threadIdx.x;   // 65536 total
    const int k = id >> 9, r = id & 511;
    out[id] = in[r * 128 + k];
}

// ---------------------------------------------------------------------------
// LSTM layer 0, weights-in-registers recurrent kernel.
// ---------------------------------------------------------------------------
__global__ __launch_bounds__(512) void lstm_rec0_kernel(
    const float* __restrict__ xseq,
    const float* __restrict__ wih0, const float* __restrict__ whh0,
    const float* __restrict__ b0, float* __restrict__ h0seq)
{
    __shared__ float hs[128][4];
    __shared__ float xb[4][16];
    __shared__ float gs[4][4][128];
    const int r  = threadIdx.x;
    const int q  = r >> 7, jj = r & 127;
    const int b4 = blockIdx.x * 4;
    const int mb = r >> 7, mj = r & 127;

    float w[128];
#pragma unroll
    for (int k = 0; k < 128; k += 4) {
        const float4 v = *(const float4*)(whh0 + (size_t)r * 128 + k);
        w[k] = v.x; w[k+1] = v.y; w[k+2] = v.z; w[k+3] = v.w;
    }
    float wx[9];
#pragma unroll
    for (int c = 0; c < 9; ++c) wx[c] = wih0[(size_t)r * 9 + c];
    const float bias = b0[r];

    float cst = 0.f;
    hs[jj][q] = 0.f;
    __syncthreads();

    for (int t = 0; t < 10; ++t) {
        if (r < 64) {
            const int b = r >> 4, c = r & 15;
            if (c < 9) xb[b][c] = xseq[((size_t)(b4 + b) * 10 + t) * 9 + c];
        }
        __syncthreads();
        float a0 = bias, a1 = bias, a2 = bias, a3 = bias;
#pragma unroll
        for (int c = 0; c < 9; ++c) {
            a0 = fmaf(wx[c], xb[0][c], a0);
            a1 = fmaf(wx[c], xb[1][c], a1);
            a2 = fmaf(wx[c], xb[2][c], a2);
            a3 = fmaf(wx[c], xb[3][c], a3);
        }
#pragma unroll
        for (int k = 0; k < 128; ++k) {
            const float4 h4 = *(const float4*)&hs[k][0];
            a0 = fmaf(w[k], h4.x, a0);
            a1 = fmaf(w[k], h4.y, a1);
            a2 = fmaf(w[k], h4.z, a2);
            a3 = fmaf(w[k], h4.w, a3);
        }
        gs[0][q][jj] = a0;
        gs[1][q][jj] = a1;
        gs[2][q][jj] = a2;
        gs[3][q][jj] = a3;
        __syncthreads();
        const float gi = gs[mb][0][mj], gf = gs[mb][1][mj];
        const float gg = gs[mb][2][mj], go = gs[mb][3][mj];
        cst = sigm(gf) * cst + sigm(gi) * tanhf(gg);
        const float hn = sigm(go) * tanhf(cst);
        hs[mj][mb] = hn;
        h0seq[((size_t)(b4 + mb) * 10 + t) * 128 + mj] = hn;
        __syncthreads();
    }
}

// ---------------------------------------------------------------------------
// LSTM layer 1.
// ---------------------------------------------------------------------------
__global__ __launch_bounds__(512) void lstm_rec1_kernel(
    const float* __restrict__ h0seq, const float* __restrict__ wih1T,
    const float* __restrict__ whh1, const float* __restrict__ b1,
    float* __restrict__ hout)
{
    __shared__ float hs[128][4];
    __shared__ float xs_[128][4];
    __shared__ float gs[4][4][128];
    const int r  = threadIdx.x;
    const int q  = r >> 7, jj = r & 127;
    const int b4 = blockIdx.x * 4;
    const int mb = r >> 7, mj = r & 127;

    float w[128];
#pragma unroll
    for (int k = 0; k < 128; k += 4) {
        const float4 v = *(const float4*)(whh1 + (size_t)r * 128 + k);
        w[k] = v.x; w[k+1] = v.y; w[k+2] = v.z; w[k+3] = v.w;
    }
    const float bias = b1[r];

    float cst = 0.f;
    hs[jj][q] = 0.f;
    __syncthreads();

    for (int t = 0; t < 10; ++t) {
        {
            const int k = r & 127, b = r >> 7;
            xs_[k][b] = h0seq[((size_t)(b4 + b) * 10 + t) * 128 + k];
        }
        __syncthreads();
        float a0 = bias, a1 = bias, a2 = bias, a3 = bias;
#pragma unroll
        for (int k = 0; k < 128; ++k) {
            const float wxv = wih1T[k * 512 + r];
            const float4 x4 = *(const float4*)&xs_[k][0];
            const float4 h4 = *(const float4*)&hs[k][0];
            a0 = fmaf(wxv, x4.x, fmaf(w[k], h4.x, a0));
            a1 = fmaf(wxv, x4.y, fmaf(w[k], h4.y, a1));
            a2 = fmaf(wxv, x4.z, fmaf(w[k], h4.z, a2));
            a3 = fmaf(wxv, x4.w, fmaf(w[k], h4.w, a3));
        }
        gs[0][q][jj] = a0;
        gs[1][q][jj] = a1;
        gs[2][q][jj] = a2;
        gs[3][q][jj] = a3;
        __syncthreads();
        const float gi = gs[mb][0][mj], gf = gs[mb][1][mj];
        const float gg = gs[mb][2][mj], go = gs[mb][3][mj];
        cst = sigm(gf) * cst + sigm(gi) * tanhf(gg);
        const float hn = sigm(go) * tanhf(cst);
        hs[mj][mb] = hn;
        if (t == 9)
            hout[(size_t)(N_DET + b4 + mb) * 256 + 128 + mj] = hn;
        __syncthreads();
    }
}

// ---------------------------------------------------------------------------
// EdgeConv fused GEMM: C[1024][512] = h @ [tw;pw]^T with routing epilogue.
// ---------------------------------------------------------------------------
__global__ __launch_bounds__(256) void ec_gemm_kernel(
    const float* __restrict__ hin,
    const float* __restrict__ tw, const float* __restrict__ tb,
    const float* __restrict__ pw, const float* __restrict__ pb,
    float* __restrict__ Abuf, float* __restrict__ Bbuf,
    float* __restrict__ phiT, float* __restrict__ hnext)
{
    __shared__ float As[16][68];
    __shared__ float Ws[16][68];
    const int bm = blockIdx.x, bn = blockIdx.y;
    const int tid = threadIdx.x;
    const int tx = tid & 15, ty = tid >> 4;
    float acc[4][4] = {};
    for (int kk = 0; kk < 256; kk += 16) {
        if (kk) __syncthreads();
#pragma unroll
        for (int i = 0; i < 4; ++i) {
            const int e = tid + 256*i;
            const int r = e >> 4, c = e & 15;
            As[c][r] = hin[(size_t)(bm*64 + r)*256 + kk + c];
            const int n = bn*64 + r;
            const float* wp = (n < 256) ? (tw + (size_t)n*256) : (pw + (size_t)(n-256)*256);
            Ws[c][r] = wp[kk + c];
        }
        __syncthreads();
#pragma unroll
        for (int k = 0; k < 16; ++k) {
            const float4 a = *(const float4*)&As[k][ty*4];
            const float4 w = *(const float4*)&Ws[k][tx*4];
            const float av[4] = {a.x, a.y, a.z, a.w};
            const float wv[4] = {w.x, w.y, w.z, w.w};
#pragma unroll
            for (int i = 0; i < 4; ++i)
#pragma unroll
                for (int jj = 0; jj < 4; ++jj)
                    acc[i][jj] = fmaf(av[i], wv[jj], acc[i][jj]);
        }
    }
    const int row0 = bm*64 + ty*4;
    const int col0 = bn*64 + tx*4;
#pragma unroll
    for (int i = 0; i < 4; ++i) {
#pragma unroll
        for (int jj = 0; jj < 4; ++jj) {
            const int row = row0 + i, col = col0 + jj;
            float v = acc[i][jj];
            if (col < 256) {
                if (row < N_DET) Abuf[(size_t)row*256 + col] = v;
                else             Bbuf[(size_t)(row - N_DET)*256 + col] = v;
            } else {
                const int o = col - 256;
                v += pb[o];
                if (row < N_DET) hnext[(size_t)row*256 + o] = fmaxf(v + tb[o], 0.f);
                else             phiT[(size_t)(row - N_DET)*256 + o] = v;
            }
        }
    }
}

// ---------------------------------------------------------------------------
// LDS-tiled masked column-max. Block = 16 m's x 32 o's; thread = (m, o-pair).
// Stages A[64][32] and aff-as-{0,-BIG}[64][16] per n-chunk, branchless inner.
// ---------------------------------------------------------------------------
#define CM_MT 16
#define CM_OT 32
#define CM_NC 64

__global__ __launch_bounds__(256) void ec_colmax_kernel(
    const float* __restrict__ aff,
    const float* __restrict__ Abuf, const float* __restrict__ Bbuf,
    const float* __restrict__ phiT, const float* __restrict__ tb,
    float* __restrict__ hnext)
{
    __shared__ float As[CM_NC][CM_OT + 4];    // stride 36: float4-aligned writes
    __shared__ float Fs[CM_NC][CM_MT + 4];    // stride 20
    const int t = threadIdx.x;
    const int mtile = blockIdx.x;             // 0..31
    const int otile = blockIdx.y;             // 0..7
    const int mi = t >> 4, oi = t & 15;

    float mx0 = -3.0e38f, mx1 = -3.0e38f;

    for (int n0 = 0; n0 < 512; n0 += CM_NC) {
        if (n0) __syncthreads();
        // stage A chunk: 64 rows x 32 cols (coalesced float4)
        {
            const int r = t >> 3, c4 = (t & 7) * 4;
#pragma unroll
            for (int rr = 0; rr < 2; ++rr) {
                const float4 v = *(const float4*)(
                    Abuf + (size_t)(n0 + rr*32 + r)*256 + otile*CM_OT + c4);
                *(float4*)&As[rr*32 + r][c4] = v;
            }
        }
        // stage aff chunk -> 0 (keep) / -3e38 (masked)
        {
            const int n = t >> 2, m4 = (t & 3) * 4;
            const float4 a = *(const float4*)(
                aff + (size_t)(n0 + n)*512 + mtile*CM_MT + m4);
            float4 f;
            f.x = (a.x > 0.f) ? 0.f : -3.0e38f;
            f.y = (a.y > 0.f) ? 0.f : -3.0e38f;
            f.z = (a.z > 0.f) ? 0.f : -3.0e38f;
            f.w = (a.w > 0.f) ? 0.f : -3.0e38f;
            *(float4*)&Fs[n][m4] = f;
        }
        __syncthreads();
#pragma unroll 4
        for (int n = 0; n < CM_NC; ++n) {
            const float f = Fs[n][mi];
            const float2 a = *(const float2*)&As[n][oi*2];
            mx0 = fmaxf(mx0, a.x + f);
            mx1 = fmaxf(mx1, a.y + f);
        }
    }

    const int m = mtile*CM_MT + mi;
    const int o = otile*CM_OT + oi*2;
    const float2 tb2 = *(const float2*)(tb + o);
    const float2 bb  = *(const float2*)(Bbuf + (size_t)m*256 + o);
    const float2 ph  = *(const float2*)(phiT + (size_t)m*256 + o);
    const float v0 = fmaxf(tb2.x, mx0 - bb.x + tb2.x);
    const float v1 = fmaxf(tb2.y, mx1 - bb.y + tb2.y);
    float2 outv;
    outv.x = fmaxf(ph.x + v0, 0.f);
    outv.y = fmaxf(ph.y + v1, 0.f);
    *(float2*)(hnext + (size_t)(N_DET + m)*256 + o) = outv;
}

// ---------------------------------------------------------------------------
// Head projection: P[1024][64] = h @ er_w1^T.
// ---------------------------------------------------------------------------
__global__ __launch_bounds__(256) void headp_kernel(
    const float* __restrict__ h, const float* __restrict__ w1, float* __restrict__ P)
{
    const int tid = threadIdx.x;
    const int o = tid & 63, rl = tid >> 6;
    const int row = blockIdx.x * 4 + rl;
    const float* hr = h + (size_t)row * 256;
    const float* wr = w1 + (size_t)o * 256;
    float s0 = 0.f, s1 = 0.f, s2 = 0.f, s3 = 0.f;
#pragma unroll
    for (int c = 0; c < 256; c += 4) {
        const float4 hv = *(const float4*)(hr + c);
        const float4 wv = *(const float4*)(wr + c);
        s0 = fmaf(hv.x, wv.x, s0);
        s1 = fmaf(hv.y, wv.y, s1);
        s2 = fmaf(hv.z, wv.z, s2);
        s3 = fmaf(hv.w, wv.w, s3);
    }
    P[(size_t)row * 64 + o] = (s0 + s1) + (s2 + s3);
}

// ---------------------------------------------------------------------------
// Pairwise affinity head.
// ---------------------------------------------------------------------------
__global__ __launch_bounds__(256) void pairwise_kernel(
    const float* __restrict__ P, const float* __restrict__ aff,
    const float* __restrict__ eb1, const float* __restrict__ ew2, const float* __restrict__ eb2,
    float* __restrict__ out)
{
    __shared__ float pd[64], sb1[64], sw2[64];
    const int n = blockIdx.y;
    const int t = threadIdx.x;
    if (t < 64)       pd[t]        = P[(size_t)n * 64 + t];
    else if (t < 128) sb1[t - 64]  = eb1[t - 64];
    else if (t < 192) sw2[t - 128] = ew2[t - 128];
    __syncthreads();
    const int m = blockIdx.x * 256 + t;
    const float* pt = P + (size_t)(N_DET + m) * 64;
    float s = eb2[0];
#pragma unroll
    for (int c = 0; c < 64; c += 4) {
        const float4 pv = *(const float4*)(pt + c);
        float e;
        e = fmaxf(pv.x - pd[c+0] + sb1[c+0], 0.f); s = fmaf(e, sw2[c+0], s);
        e = fmaxf(pv.y - pd[c+1] + sb1[c+1], 0.f); s = fmaf(e, sw2[c+1], s);
        e = fmaxf(pv.z - pd[c+2] + sb1[c+2], 0.f); s = fmaf(e, sw2[c+2], s);
        e = fmaxf(pv.w - pd[c+3] + sb1[c+3], 0.f); s = fmaf(e, sw2[c+3], s);
    }
    const float r = 1.f / (1.f + expf(-s));
    const float v = aff[(size_t)n * 512 + m] * r;
    out[(size_t)n * 512 + m] = (v == 0.f) ? 99.f : v;
}

// ---------------------------------------------------------------------------
extern "C" void kernel_launch(void* const* d_in, const int* in_sizes, int n_in,
                              void* d_out, int out_size, void* d_ws, size_t ws_size,
                              hipStream_t stream)
{
    (void)in_sizes; (void)n_in; (void)out_size; (void)ws_size;

    const float* det_pc  = (const float*)d_in[0];
    const float* det_box = (const float*)d_in[1];
    const float* trk_pc  = (const float*)d_in[2];
    const float* trk_box = (const float*)d_in[3];
    const float* aff     = (const float*)d_in[4];
    const float* pn_w1  = (const float*)d_in[6];
    const float* pn_b1  = (const float*)d_in[7];
    const float* pn_w2  = (const float*)d_in[8];
    const float* pn_b2  = (const float*)d_in[9];
    const float* pn_w3  = (const float*)d_in[10];
    const float* pn_b3  = (const float*)d_in[11];
    const float* mlp_w1 = (const float*)d_in[12];
    const float* mlp_b1 = (const float*)d_in[13];
    const float* mlp_w2 = (const float*)d_in[14];
    const float* mlp_b2 = (const float*)d_in[15];
    const float* l0_wih = (const float*)d_in[16];
    const float* l0_whh = (const float*)d_in[17];
    const float* l0_b   = (const float*)d_in[18];
    const float* l1_wih = (const float*)d_in[19];
    const float* l1_whh = (const float*)d_in[20];
    const float* l1_b   = (const float*)d_in[21];
    const float* ec_tw  = (const float*)d_in[22];
    const float* ec_tb  = (const float*)d_in[23];
    const float* ec_pw  = (const float*)d_in[24];
    const float* ec_pb  = (const float*)d_in[25];
    const float* er_w1  = (const float*)d_in[26];
    const float* er_b1  = (const float*)d_in[27];
    const float* er_w2  = (const float*)d_in[28];
    const float* er_b2  = (const float*)d_in[29];

    float* ws    = (float*)d_ws;
    float* hA    = ws;                    // [1024][256]
    float* hB    = hA + 1024*256;         // [1024][256]
    float* Abuf  = hB + 1024*256;         // [512][256]
    float* Bbuf  = Abuf + 512*256;        // [512][256]
    float* phiT  = Bbuf + 512*256;        // [512][256]
    float* P     = phiT + 512*256;        // [1024][64]
    float* h0seq = P + 1024*64;           // [512][10][128]
    float* wih1T = h0seq + 512*10*128;    // [128][512]
    unsigned short* wfrag = (unsigned short*)(wih1T + 128*512);  // 48*64*8 bf16

    pn_wprep_kernel<<<48, 64, 0, stream>>>(pn_w2, pn_w3, wfrag);
    pointnet_mfma_kernel<<<1024, 256, 0, stream>>>(det_pc, trk_pc, pn_w1, pn_b1,
                                                   wfrag, pn_b2, pn_b3, hA);
    detmlp_kernel<<<512, 128, 0, stream>>>(det_box, mlp_w1, mlp_b1, mlp_w2, mlp_b2, hA);
    transpose_wih1_kernel<<<256, 256, 0, stream>>>(l1_wih, wih1T);
    lstm_rec0_kernel<<<128, 512, 0, stream>>>(trk_box, l0_wih, l0_whh, l0_b, h0seq);
    lstm_rec1_kernel<<<128, 512, 0, stream>>>(h0seq, wih1T, l1_whh, l1_b, hA);

    float* hcur = hA;
    float* hnext = hB;
    for (int k = 0; k < 4; ++k) {
        const float* tw = ec_tw + (size_t)k * 256 * 256;
        const float* tb = ec_tb + (size_t)k * 256;
        const float* pw = ec_pw + (size_t)k * 256 * 256;
        const float* pb = ec_pb + (size_t)k * 256;
        ec_gemm_kernel<<<dim3(16, 8), 256, 0, stream>>>(hcur, tw, tb, pw, pb,
                                                        Abuf, Bbuf, phiT, hnext);
        ec_colmax_kernel<<<dim3(32, 8), 256, 0, stream>>>(aff, Abuf, Bbuf, phiT, tb, hnext);
        float* tmp = hcur; hcur = hnext; hnext = tmp;
    }

    headp_kernel<<<256, 256, 0, stream>>>(hcur, er_w1, P);
    pairwise_kernel<<<dim3(2, 512), 256, 0, stream>>>(P, aff, er_b1, er_w2, er_b2,
                                                      (float*)d_out);
}

// Round 5
// 413.798 us; speedup vs baseline: 10.2209x; 1.1764x over previous
//
#include <hip/hip_runtime.h>
#include <math.h>

#define N_DET 512
#define N_TRK 512
#define NPTS  256

typedef __attribute__((ext_vector_type(8))) short short8;
typedef __attribute__((ext_vector_type(4))) float f32x4;

__device__ __forceinline__ float sigm(float x) { return 1.f / (1.f + expf(-x)); }

__device__ __forceinline__ unsigned short f2bf(float f) {
    unsigned u = __float_as_uint(f);
    u += 0x7FFF + ((u >> 16) & 1);          // round-to-nearest-even
    return (unsigned short)(u >> 16);
}

// ---------------------------------------------------------------------------
// Pack pointnet w2/w3 into MFMA B-fragment-major bf16.
// ---------------------------------------------------------------------------
__global__ __launch_bounds__(64) void pn_wprep_kernel(
    const float* __restrict__ w2, const float* __restrict__ w3,
    unsigned short* __restrict__ wfrag)
{
    const int f = blockIdx.x;          // 48
    const int lane = threadIdx.x;      // 64
    const int lm = lane & 15, lg = lane >> 4;
    const float* src;
    if (f < 16) {
        const int s = f >> 3, n = f & 7;
        src = w2 + (size_t)(n*16 + lm)*64 + s*32 + lg*8;
    } else {
        const int f2 = f - 16, s = f2 >> 3, n = f2 & 7;
        src = w3 + (size_t)(n*16 + lm)*128 + s*32 + lg*8;
    }
    short8 v;
#pragma unroll
    for (int j = 0; j < 8; ++j) v[j] = (short)f2bf(src[j]);
    *reinterpret_cast<short8*>(wfrag + ((size_t)f*64 + lane)*8) = v;
}

// ---------------------------------------------------------------------------
// PointNet fused MFMA kernel: one box per block, 256 threads (4 waves).
// ---------------------------------------------------------------------------
__global__ __launch_bounds__(256, 1) void pointnet_mfma_kernel(
    const float* __restrict__ det_pc, const float* __restrict__ trk_pc,
    const float* __restrict__ w1, const float* __restrict__ b1,
    const unsigned short* __restrict__ wfrag,
    const float* __restrict__ b2, const float* __restrict__ b3,
    float* __restrict__ hout)
{
    __shared__ unsigned short h1s[256*72];
    __shared__ unsigned short h2s[256*136];
    __shared__ float wmaxs[4][128];

    const int tid = threadIdx.x;
    const int box = blockIdx.x;
    const int lane = tid & 63, w = tid >> 6;
    const int lm = lane & 15, lg = lane >> 4;

    // ---- L1: thread = point ----
    const float* pc = (box < N_DET) ? det_pc + ((size_t)box*NPTS + tid)*3
                                    : trk_pc + ((size_t)(box - N_DET)*NPTS + tid)*3;
    const float x = pc[0], y = pc[1], z = pc[2];
#pragma unroll
    for (int j = 0; j < 8; ++j) {
        short8 v;
#pragma unroll
        for (int o = 0; o < 8; ++o) {
            const int ch = j*8 + o;
            float s = fmaf(w1[ch*3+0], x, fmaf(w1[ch*3+1], y,
                        fmaf(w1[ch*3+2], z, b1[ch])));
            v[o] = (short)f2bf(fmaxf(s, 0.f));
        }
        *reinterpret_cast<short8*>(&h1s[tid*72 + j*8]) = v;
    }
    __syncthreads();

    // ---- L2: [64 pts x 64] @ w2^T -> h2 ----
    short8 w2f[16];
#pragma unroll
    for (int f = 0; f < 16; ++f)
        w2f[f] = *reinterpret_cast<const short8*>(wfrag + ((size_t)f*64 + lane)*8);
    float b2v[8];
#pragma unroll
    for (int n = 0; n < 8; ++n) b2v[n] = b2[n*16 + lm];

#pragma unroll
    for (int t = 0; t < 4; ++t) {
        const int arow = w*64 + t*16 + lm;
        const short8 a0 = *reinterpret_cast<const short8*>(&h1s[arow*72 + lg*8]);
        const short8 a1 = *reinterpret_cast<const short8*>(&h1s[arow*72 + 32 + lg*8]);
        const int wrow = w*64 + t*16 + lg*4;
#pragma unroll
        for (int n = 0; n < 8; ++n) {
            f32x4 acc = {0.f, 0.f, 0.f, 0.f};
            acc = __builtin_amdgcn_mfma_f32_16x16x32_bf16(a0, w2f[n],     acc, 0, 0, 0);
            acc = __builtin_amdgcn_mfma_f32_16x16x32_bf16(a1, w2f[8 + n], acc, 0, 0, 0);
#pragma unroll
            for (int r = 0; r < 4; ++r) {
                const float v = fmaxf(acc[r] + b2v[n], 0.f);
                h2s[(wrow + r)*136 + n*16 + lm] = f2bf(v);
            }
        }
    }
    __syncthreads();

    // ---- L3: [64 pts x 128] @ w3^T, fused maxpool ----
    short8 w3f[32];
#pragma unroll
    for (int f = 0; f < 32; ++f)
        w3f[f] = *reinterpret_cast<const short8*>(wfrag + ((size_t)(16 + f)*64 + lane)*8);

    float pm[8];
#pragma unroll
    for (int n = 0; n < 8; ++n) pm[n] = -3.0e38f;

#pragma unroll
    for (int t = 0; t < 4; ++t) {
        const int arow = w*64 + t*16 + lm;
        const short8 a0 = *reinterpret_cast<const short8*>(&h2s[arow*136 +  0 + lg*8]);
        const short8 a1 = *reinterpret_cast<const short8*>(&h2s[arow*136 + 32 + lg*8]);
        const short8 a2 = *reinterpret_cast<const short8*>(&h2s[arow*136 + 64 + lg*8]);
        const short8 a3 = *reinterpret_cast<const short8*>(&h2s[arow*136 + 96 + lg*8]);
#pragma unroll
        for (int n = 0; n < 8; ++n) {
            f32x4 acc = {0.f, 0.f, 0.f, 0.f};
            acc = __builtin_amdgcn_mfma_f32_16x16x32_bf16(a0, w3f[n],      acc, 0, 0, 0);
            acc = __builtin_amdgcn_mfma_f32_16x16x32_bf16(a1, w3f[8 + n],  acc, 0, 0, 0);
            acc = __builtin_amdgcn_mfma_f32_16x16x32_bf16(a2, w3f[16 + n], acc, 0, 0, 0);
            acc = __builtin_amdgcn_mfma_f32_16x16x32_bf16(a3, w3f[24 + n], acc, 0, 0, 0);
#pragma unroll
            for (int r = 0; r < 4; ++r) pm[n] = fmaxf(pm[n], acc[r]);
        }
    }
#pragma unroll
    for (int n = 0; n < 8; ++n) {
        float v = pm[n];
        v = fmaxf(v, __shfl_xor(v, 16, 64));
        v = fmaxf(v, __shfl_xor(v, 32, 64));
        pm[n] = v;
    }
    if (lg == 0) {
#pragma unroll
        for (int n = 0; n < 8; ++n) wmaxs[w][n*16 + lm] = pm[n];
    }
    __syncthreads();
    if (tid < 128) {
        const float m = fmaxf(fmaxf(wmaxs[0][tid], wmaxs[1][tid]),
                              fmaxf(wmaxs[2][tid], wmaxs[3][tid]));
        hout[(size_t)box*256 + tid] = fmaxf(m + b3[tid], 0.f);
    }
}

// ---------------------------------------------------------------------------
// det motion MLP: 9 -> 64 (relu) -> 128. One block per det.
// ---------------------------------------------------------------------------
__global__ __launch_bounds__(128) void detmlp_kernel(
    const float* __restrict__ boxes,
    const float* __restrict__ w1, const float* __restrict__ b1,
    const float* __restrict__ w2, const float* __restrict__ b2,
    float* __restrict__ hout)
{
    __shared__ float xb[9];
    __shared__ float h1[64];
    const int b = blockIdx.x, t = threadIdx.x;
    if (t < 9) xb[t] = boxes[b*9 + t];
    __syncthreads();
    if (t < 64) {
        float s = b1[t];
#pragma unroll
        for (int c = 0; c < 9; ++c) s = fmaf(w1[t*9+c], xb[c], s);
        h1[t] = fmaxf(s, 0.f);
    }
    __syncthreads();
    float s = b2[t];
    const float* wr = w2 + t*64;
#pragma unroll
    for (int c = 0; c < 64; ++c) s = fmaf(wr[c], h1[c], s);
    hout[(size_t)b * 256 + 128 + t] = s;
}

// ---------------------------------------------------------------------------
__global__ __launch_bounds__(256) void transpose_wih1_kernel(
    const float* __restrict__ in, float* __restrict__ out)
{
    const int id = blockIdx.x * 256 + threadIdx.x;   // 65536 total
    const int k = id >> 9, r = id & 511;
    out[id] = in[r * 128 + k];
}

// ---------------------------------------------------------------------------
// LSTM layer 0: 2 batches/block (256 blocks), thread r owns gate row r
// (whh0 row + wih0 row in registers). h-state broadcast via LDS.
// ---------------------------------------------------------------------------
__global__ __launch_bounds__(512) void lstm_rec0_kernel(
    const float* __restrict__ xseq,
    const float* __restrict__ wih0, const float* __restrict__ whh0,
    const float* __restrict__ b0, float* __restrict__ h0seq)
{
    __shared__ float hs[128][2];
    __shared__ float xb[2][12];
    __shared__ float gs[4][2][128];
    const int r  = threadIdx.x;
    const int b2 = blockIdx.x * 2;
    const int q  = r >> 7 & 3, jj = r & 127;
    const int mb = r >> 7, mj = r & 127;     // mixer mapping (r < 256)

    float w[128];
#pragma unroll
    for (int k = 0; k < 128; k += 4) {
        const float4 v = *(const float4*)(whh0 + (size_t)r * 128 + k);
        w[k] = v.x; w[k+1] = v.y; w[k+2] = v.z; w[k+3] = v.w;
    }
    float wx[9];
#pragma unroll
    for (int c = 0; c < 9; ++c) wx[c] = wih0[(size_t)r * 9 + c];
    const float bias = b0[r];

    float cst = 0.f;
    if (r < 256) hs[mj][mb] = 0.f;
    __syncthreads();

    for (int t = 0; t < 10; ++t) {
        if (r < 18) xb[r / 9][r % 9] = xseq[((size_t)(b2 + r / 9) * 10 + t) * 9 + r % 9];
        __syncthreads();
        float a0 = bias, a1 = bias;
#pragma unroll
        for (int c = 0; c < 9; ++c) {
            a0 = fmaf(wx[c], xb[0][c], a0);
            a1 = fmaf(wx[c], xb[1][c], a1);
        }
#pragma unroll
        for (int k = 0; k < 128; ++k) {
            const float2 h2 = *(const float2*)&hs[k][0];
            a0 = fmaf(w[k], h2.x, a0);
            a1 = fmaf(w[k], h2.y, a1);
        }
        gs[q][0][jj] = a0;
        gs[q][1][jj] = a1;
        __syncthreads();
        if (r < 256) {
            const float gi = gs[0][mb][mj], gf = gs[1][mb][mj];
            const float gg = gs[2][mb][mj], go = gs[3][mb][mj];
            cst = sigm(gf) * cst + sigm(gi) * tanhf(gg);
            const float hn = sigm(go) * tanhf(cst);
            hs[mj][mb] = hn;
            h0seq[((size_t)(b2 + mb) * 10 + t) * 128 + mj] = hn;
        }
        __syncthreads();
    }
}

// ---------------------------------------------------------------------------
// LSTM layer 1: 2 batches/block (256 blocks). whh1 row in registers; x-part
// weight streamed coalesced from wih1T (L2-resident).
// ---------------------------------------------------------------------------
__global__ __launch_bounds__(512) void lstm_rec1_kernel(
    const float* __restrict__ h0seq, const float* __restrict__ wih1T,
    const float* __restrict__ whh1, const float* __restrict__ b1,
    float* __restrict__ hout)
{
    __shared__ float hs[128][2];
    __shared__ float xs_[128][2];
    __shared__ float gs[4][2][128];
    const int r  = threadIdx.x;
    const int b2 = blockIdx.x * 2;
    const int q  = r >> 7 & 3, jj = r & 127;
    const int mb = r >> 7, mj = r & 127;     // mixer mapping (r < 256)

    float w[128];
#pragma unroll
    for (int k = 0; k < 128; k += 4) {
        const float4 v = *(const float4*)(whh1 + (size_t)r * 128 + k);
        w[k] = v.x; w[k+1] = v.y; w[k+2] = v.z; w[k+3] = v.w;
    }
    const float bias = b1[r];

    float cst = 0.f;
    if (r < 256) hs[mj][mb] = 0.f;
    __syncthreads();

    for (int t = 0; t < 10; ++t) {
        if (r < 256)
            xs_[mj][mb] = h0seq[((size_t)(b2 + mb) * 10 + t) * 128 + mj];
        __syncthreads();
        float a0 = bias, a1 = bias;
#pragma unroll
        for (int k = 0; k < 128; ++k) {
            const float wxv = wih1T[k * 512 + r];
            const float2 x2 = *(const float2*)&xs_[k][0];
            const float2 h2 = *(const float2*)&hs[k][0];
            a0 = fmaf(wxv, x2.x, fmaf(w[k], h2.x, a0));
            a1 = fmaf(wxv, x2.y, fmaf(w[k], h2.y, a1));
        }
        gs[q][0][jj] = a0;
        gs[q][1][jj] = a1;
        __syncthreads();
        if (r < 256) {
            const float gi = gs[0][mb][mj], gf = gs[1][mb][mj];
            const float gg = gs[2][mb][mj], go = gs[3][mb][mj];
            cst = sigm(gf) * cst + sigm(gi) * tanhf(gg);
            const float hn = sigm(go) * tanhf(cst);
            hs[mj][mb] = hn;
            if (t == 9)
                hout[(size_t)(N_DET + b2 + mb) * 256 + 128 + mj] = hn;
        }
        __syncthreads();
    }
}

// ---------------------------------------------------------------------------
// EdgeConv fused GEMM: C[1024][512] = h @ [tw;pw]^T with routing epilogue.
// ---------------------------------------------------------------------------
__global__ __launch_bounds__(256) void ec_gemm_kernel(
    const float* __restrict__ hin,
    const float* __restrict__ tw, const float* __restrict__ tb,
    const float* __restrict__ pw, const float* __restrict__ pb,
    float* __restrict__ Abuf, float* __restrict__ Bbuf,
    float* __restrict__ phiT, float* __restrict__ hnext)
{
    __shared__ float As[16][68];
    __shared__ float Ws[16][68];
    const int bm = blockIdx.x, bn = blockIdx.y;
    const int tid = threadIdx.x;
    const int tx = tid & 15, ty = tid >> 4;
    float acc[4][4] = {};
    for (int kk = 0; kk < 256; kk += 16) {
        if (kk) __syncthreads();
#pragma unroll
        for (int i = 0; i < 4; ++i) {
            const int e = tid + 256*i;
            const int r = e >> 4, c = e & 15;
            As[c][r] = hin[(size_t)(bm*64 + r)*256 + kk + c];
            const int n = bn*64 + r;
            const float* wp = (n < 256) ? (tw + (size_t)n*256) : (pw + (size_t)(n-256)*256);
            Ws[c][r] = wp[kk + c];
        }
        __syncthreads();
#pragma unroll
        for (int k = 0; k < 16; ++k) {
            const float4 a = *(const float4*)&As[k][ty*4];
            const float4 w = *(const float4*)&Ws[k][tx*4];
            const float av[4] = {a.x, a.y, a.z, a.w};
            const float wv[4] = {w.x, w.y, w.z, w.w};
#pragma unroll
            for (int i = 0; i < 4; ++i)
#pragma unroll
                for (int jj = 0; jj < 4; ++jj)
                    acc[i][jj] = fmaf(av[i], wv[jj], acc[i][jj]);
        }
    }
    const int row0 = bm*64 + ty*4;
    const int col0 = bn*64 + tx*4;
#pragma unroll
    for (int i = 0; i < 4; ++i) {
#pragma unroll
        for (int jj = 0; jj < 4; ++jj) {
            const int row = row0 + i, col = col0 + jj;
            float v = acc[i][jj];
            if (col < 256) {
                if (row < N_DET) Abuf[(size_t)row*256 + col] = v;
                else             Bbuf[(size_t)(row - N_DET)*256 + col] = v;
            } else {
                const int o = col - 256;
                v += pb[o];
                if (row < N_DET) hnext[(size_t)row*256 + o] = fmaxf(v + tb[o], 0.f);
                else             phiT[(size_t)(row - N_DET)*256 + o] = v;
            }
        }
    }
}

// ---------------------------------------------------------------------------
// LDS-tiled masked column-max. Block = 16 m's x 32 o's; thread = (m, o-pair).
// ---------------------------------------------------------------------------
#define CM_MT 16
#define CM_OT 32
#define CM_NC 64

__global__ __launch_bounds__(256) void ec_colmax_kernel(
    const float* __restrict__ aff,
    const float* __restrict__ Abuf, const float* __restrict__ Bbuf,
    const float* __restrict__ phiT, const float* __restrict__ tb,
    float* __restrict__ hnext)
{
    __shared__ float As[CM_NC][CM_OT + 4];
    __shared__ float Fs[CM_NC][CM_MT + 4];
    const int t = threadIdx.x;
    const int mtile = blockIdx.x;
    const int otile = blockIdx.y;
    const int mi = t >> 4, oi = t & 15;

    float mx0 = -3.0e38f, mx1 = -3.0e38f;

    for (int n0 = 0; n0 < 512; n0 += CM_NC) {
        if (n0) __syncthreads();
        {
            const int r = t >> 3, c4 = (t & 7) * 4;
#pragma unroll
            for (int rr = 0; rr < 2; ++rr) {
                const float4 v = *(const float4*)(
                    Abuf + (size_t)(n0 + rr*32 + r)*256 + otile*CM_OT + c4);
                *(float4*)&As[rr*32 + r][c4] = v;
            }
        }
        {
            const int n = t >> 2, m4 = (t & 3) * 4;
            const float4 a = *(const float4*)(
                aff + (size_t)(n0 + n)*512 + mtile*CM_MT + m4);
            float4 f;
            f.x = (a.x > 0.f) ? 0.f : -3.0e38f;
            f.y = (a.y > 0.f) ? 0.f : -3.0e38f;
            f.z = (a.z > 0.f) ? 0.f : -3.0e38f;
            f.w = (a.w > 0.f) ? 0.f : -3.0e38f;
            *(float4*)&Fs[n][m4] = f;
        }
        __syncthreads();
#pragma unroll 4
        for (int n = 0; n < CM_NC; ++n) {
            const float f = Fs[n][mi];
            const float2 a = *(const float2*)&As[n][oi*2];
            mx0 = fmaxf(mx0, a.x + f);
            mx1 = fmaxf(mx1, a.y + f);
        }
    }

    const int m = mtile*CM_MT + mi;
    const int o = otile*CM_OT + oi*2;
    const float2 tb2 = *(const float2*)(tb + o);
    const float2 bb  = *(const float2*)(Bbuf + (size_t)m*256 + o);
    const float2 ph  = *(const float2*)(phiT + (size_t)m*256 + o);
    const float v0 = fmaxf(tb2.x, mx0 - bb.x + tb2.x);
    const float v1 = fmaxf(tb2.y, mx1 - bb.y + tb2.y);
    float2 outv;
    outv.x = fmaxf(ph.x + v0, 0.f);
    outv.y = fmaxf(ph.y + v1, 0.f);
    *(float2*)(hnext + (size_t)(N_DET + m)*256 + o) = outv;
}

// ---------------------------------------------------------------------------
// Head projection: P[1024][64] = h @ er_w1^T.
// ---------------------------------------------------------------------------
__global__ __launch_bounds__(256) void headp_kernel(
    const float* __restrict__ h, const float* __restrict__ w1, float* __restrict__ P)
{
    const int tid = threadIdx.x;
    const int o = tid & 63, rl = tid >> 6;
    const int row = blockIdx.x * 4 + rl;
    const float* hr = h + (size_t)row * 256;
    const float* wr = w1 + (size_t)o * 256;
    float s0 = 0.f, s1 = 0.f, s2 = 0.f, s3 = 0.f;
#pragma unroll
    for (int c = 0; c < 256; c += 4) {
        const float4 hv = *(const float4*)(hr + c);
        const float4 wv = *(const float4*)(wr + c);
        s0 = fmaf(hv.x, wv.x, s0);
        s1 = fmaf(hv.y, wv.y, s1);
        s2 = fmaf(hv.z, wv.z, s2);
        s3 = fmaf(hv.w, wv.w, s3);
    }
    P[(size_t)row * 64 + o] = (s0 + s1) + (s2 + s3);
}

// ---------------------------------------------------------------------------
// Pairwise affinity head.
// ---------------------------------------------------------------------------
__global__ __launch_bounds__(256) void pairwise_kernel(
    const float* __restrict__ P, const float* __restrict__ aff,
    const float* __restrict__ eb1, const float* __restrict__ ew2, const float* __restrict__ eb2,
    float* __restrict__ out)
{
    __shared__ float pd[64], sb1[64], sw2[64];
    const int n = blockIdx.y;
    const int t = threadIdx.x;
    if (t < 64)       pd[t]        = P[(size_t)n * 64 + t];
    else if (t < 128) sb1[t - 64]  = eb1[t - 64];
    else if (t < 192) sw2[t - 128] = ew2[t - 128];
    __syncthreads();
    const int m = blockIdx.x * 256 + t;
    const float* pt = P + (size_t)(N_DET + m) * 64;
    float s = eb2[0];
#pragma unroll
    for (int c = 0; c < 64; c += 4) {
        const float4 pv = *(const float4*)(pt + c);
        float e;
        e = fmaxf(pv.x - pd[c+0] + sb1[c+0], 0.f); s = fmaf(e, sw2[c+0], s);
        e = fmaxf(pv.y - pd[c+1] + sb1[c+1], 0.f); s = fmaf(e, sw2[c+1], s);
        e = fmaxf(pv.z - pd[c+2] + sb1[c+2], 0.f); s = fmaf(e, sw2[c+2], s);
        e = fmaxf(pv.w - pd[c+3] + sb1[c+3], 0.f); s = fmaf(e, sw2[c+3], s);
    }
    const float r = 1.f / (1.f + expf(-s));
    const float v = aff[(size_t)n * 512 + m] * r;
    out[(size_t)n * 512 + m] = (v == 0.f) ? 99.f : v;
}

// ---------------------------------------------------------------------------
extern "C" void kernel_launch(void* const* d_in, const int* in_sizes, int n_in,
                              void* d_out, int out_size, void* d_ws, size_t ws_size,
                              hipStream_t stream)
{
    (void)in_sizes; (void)n_in; (void)out_size; (void)ws_size;

    const float* det_pc  = (const float*)d_in[0];
    const float* det_box = (const float*)d_in[1];
    const float* trk_pc  = (const float*)d_in[2];
    const float* trk_box = (const float*)d_in[3];
    const float* aff     = (const float*)d_in[4];
    const float* pn_w1  = (const float*)d_in[6];
    const float* pn_b1  = (const float*)d_in[7];
    const float* pn_w2  = (const float*)d_in[8];
    const float* pn_b2  = (const float*)d_in[9];
    const float* pn_w3  = (const float*)d_in[10];
    const float* pn_b3  = (const float*)d_in[11];
    const float* mlp_w1 = (const float*)d_in[12];
    const float* mlp_b1 = (const float*)d_in[13];
    const float* mlp_w2 = (const float*)d_in[14];
    const float* mlp_b2 = (const float*)d_in[15];
    const float* l0_wih = (const float*)d_in[16];
    const float* l0_whh = (const float*)d_in[17];
    const float* l0_b   = (const float*)d_in[18];
    const float* l1_wih = (const float*)d_in[19];
    const float* l1_whh = (const float*)d_in[20];
    const float* l1_b   = (const float*)d_in[21];
    const float* ec_tw  = (const float*)d_in[22];
    const float* ec_tb  = (const float*)d_in[23];
    const float* ec_pw  = (const float*)d_in[24];
    const float* ec_pb  = (const float*)d_in[25];
    const float* er_w1  = (const float*)d_in[26];
    const float* er_b1  = (const float*)d_in[27];
    const float* er_w2  = (const float*)d_in[28];
    const float* er_b2  = (const float*)d_in[29];

    float* ws    = (float*)d_ws;
    float* hA    = ws;                    // [1024][256]
    float* hB    = hA + 1024*256;         // [1024][256]
    float* Abuf  = hB + 1024*256;         // [512][256]
    float* Bbuf  = Abuf + 512*256;        // [512][256]
    float* phiT  = Bbuf + 512*256;        // [512][256]
    float* P     = phiT + 512*256;        // [1024][64]
    float* h0seq = P + 1024*64;           // [512][10][128]
    float* wih1T = h0seq + 512*10*128;    // [128][512]
    unsigned short* wfrag = (unsigned short*)(wih1T + 128*512);  // 48*64*8 bf16

    pn_wprep_kernel<<<48, 64, 0, stream>>>(pn_w2, pn_w3, wfrag);
    pointnet_mfma_kernel<<<1024, 256, 0, stream>>>(det_pc, trk_pc, pn_w1, pn_b1,
                                                   wfrag, pn_b2, pn_b3, hA);
    detmlp_kernel<<<512, 128, 0, stream>>>(det_box, mlp_w1, mlp_b1, mlp_w2, mlp_b2, hA);
    transpose_wih1_kernel<<<256, 256, 0, stream>>>(l1_wih, wih1T);
    lstm_rec0_kernel<<<256, 512, 0, stream>>>(trk_box, l0_wih, l0_whh, l0_b, h0seq);
    lstm_rec1_kernel<<<256, 512, 0, stream>>>(h0seq, wih1T, l1_whh, l1_b, hA);

    float* hcur = hA;
    float* hnext = hB;
    for (int k = 0; k < 4; ++k) {
        const float* tw = ec_tw + (size_t)k * 256 * 256;
        const float* tb = ec_tb + (size_t)k * 256;
        const float* pw = ec_pw + (size_t)k * 256 * 256;
        const float* pb = ec_pb + (size_t)k * 256;
        ec_gemm_kernel<<<dim3(16, 8), 256, 0, stream>>>(hcur, tw, tb, pw, pb,
                                                        Abuf, Bbuf, phiT, hnext);
        ec_colmax_kernel<<<dim3(32, 8), 256, 0, stream>>>(aff, Abuf, Bbuf, phiT, tb, hnext);
        float* tmp = hcur; hcur = hnext; hnext = tmp;
    }

    headp_kernel<<<256, 256, 0, stream>>>(hcur, er_w1, P);
    pairwise_kernel<<<dim3(2, 512), 256, 0, stream>>>(P, aff, er_b1, er_w2, er_b2,
                                                      (float*)d_out);
}

// Round 6
// 382.454 us; speedup vs baseline: 11.0585x; 1.0820x over previous
//
#include <hip/hip_runtime.h>
#include <math.h>

#define N_DET 512
#define N_TRK 512
#define NPTS  256

typedef __attribute__((ext_vector_type(8))) short short8;
typedef __attribute__((ext_vector_type(4))) float f32x4;
typedef unsigned short ushort_t;

__device__ __forceinline__ float sigm(float x) { return 1.f / (1.f + expf(-x)); }

__device__ __forceinline__ unsigned short f2bf(float f) {
    unsigned u = __float_as_uint(f);
    u += 0x7FFF + ((u >> 16) & 1);          // round-to-nearest-even
    return (unsigned short)(u >> 16);
}
__device__ __forceinline__ float bf2f(unsigned short h) {
    return __uint_as_float(((unsigned)h) << 16);
}

// ---------------------------------------------------------------------------
// Pack pointnet w2/w3 into MFMA B-fragment-major bf16.
// ---------------------------------------------------------------------------
__global__ __launch_bounds__(64) void pn_wprep_kernel(
    const float* __restrict__ w2, const float* __restrict__ w3,
    unsigned short* __restrict__ wfrag)
{
    const int f = blockIdx.x;          // 48
    const int lane = threadIdx.x;      // 64
    const int lm = lane & 15, lg = lane >> 4;
    const float* src;
    if (f < 16) {
        const int s = f >> 3, n = f & 7;
        src = w2 + (size_t)(n*16 + lm)*64 + s*32 + lg*8;
    } else {
        const int f2 = f - 16, s = f2 >> 3, n = f2 & 7;
        src = w3 + (size_t)(n*16 + lm)*128 + s*32 + lg*8;
    }
    short8 v;
#pragma unroll
    for (int j = 0; j < 8; ++j) v[j] = (short)f2bf(src[j]);
    *reinterpret_cast<short8*>(wfrag + ((size_t)f*64 + lane)*8) = v;
}

// ---------------------------------------------------------------------------
// Pack EdgeConv W=[tw;pw] (per layer, [512][256]) into frag-major bf16 hi/lo.
// Frag id = layer*256 + ntile*8 + kf; lane l: col=ntile*16+(l&15), k=kf*32+(l>>4)*8+j
// ---------------------------------------------------------------------------
__global__ __launch_bounds__(64) void ec_wprep_kernel(
    const float* __restrict__ tw, const float* __restrict__ pw,
    unsigned short* __restrict__ whi, unsigned short* __restrict__ wlo)
{
    const int id = blockIdx.x;                 // 1024 = 4 layers * 32 ntiles * 8 kf
    const int layer = id >> 8;
    const int ntile = (id >> 3) & 31, kf = id & 7;
    const int lane = threadIdx.x;
    const int lm = lane & 15, lg = lane >> 4;
    const int col = ntile*16 + lm, k = kf*32 + lg*8;
    const float* src = (col < 256)
        ? tw + ((size_t)layer*256 + col)*256 + k
        : pw + ((size_t)layer*256 + (col - 256))*256 + k;
    short8 hi, lo;
#pragma unroll
    for (int j = 0; j < 8; ++j) {
        const float f = src[j];
        const unsigned short h = f2bf(f);
        hi[j] = (short)h;
        lo[j] = (short)f2bf(f - bf2f(h));
    }
    const size_t off = ((size_t)id*64 + lane)*8;
    *reinterpret_cast<short8*>(whi + off) = hi;
    *reinterpret_cast<short8*>(wlo + off) = lo;
}

// ---------------------------------------------------------------------------
// h (fp32 [1024][256]) -> split-bf16 shadow (hi, lo).
// ---------------------------------------------------------------------------
__global__ __launch_bounds__(256) void h2bf_kernel(
    const float* __restrict__ h,
    unsigned short* __restrict__ hi, unsigned short* __restrict__ lo)
{
    const int id = blockIdx.x * 256 + threadIdx.x;   // 65536, 4 elems each
    const float4 v = *(const float4*)(h + (size_t)id*4);
    ushort_t h4[4], l4[4];
    const float vv[4] = {v.x, v.y, v.z, v.w};
#pragma unroll
    for (int j = 0; j < 4; ++j) {
        h4[j] = f2bf(vv[j]);
        l4[j] = f2bf(vv[j] - bf2f(h4[j]));
    }
    *(ulong1*)(hi + (size_t)id*4) = *(ulong1*)h4;
    *(ulong1*)(lo + (size_t)id*4) = *(ulong1*)l4;
}

// ---------------------------------------------------------------------------
// PointNet fused MFMA kernel: one box per block, 256 threads (4 waves).
// ---------------------------------------------------------------------------
__global__ __launch_bounds__(256, 1) void pointnet_mfma_kernel(
    const float* __restrict__ det_pc, const float* __restrict__ trk_pc,
    const float* __restrict__ w1, const float* __restrict__ b1,
    const unsigned short* __restrict__ wfrag,
    const float* __restrict__ b2, const float* __restrict__ b3,
    float* __restrict__ hout)
{
    __shared__ unsigned short h1s[256*72];
    __shared__ unsigned short h2s[256*136];
    __shared__ float wmaxs[4][128];

    const int tid = threadIdx.x;
    const int box = blockIdx.x;
    const int lane = tid & 63, w = tid >> 6;
    const int lm = lane & 15, lg = lane >> 4;

    // ---- L1: thread = point ----
    const float* pc = (box < N_DET) ? det_pc + ((size_t)box*NPTS + tid)*3
                                    : trk_pc + ((size_t)(box - N_DET)*NPTS + tid)*3;
    const float x = pc[0], y = pc[1], z = pc[2];
#pragma unroll
    for (int j = 0; j < 8; ++j) {
        short8 v;
#pragma unroll
        for (int o = 0; o < 8; ++o) {
            const int ch = j*8 + o;
            float s = fmaf(w1[ch*3+0], x, fmaf(w1[ch*3+1], y,
                        fmaf(w1[ch*3+2], z, b1[ch])));
            v[o] = (short)f2bf(fmaxf(s, 0.f));
        }
        *reinterpret_cast<short8*>(&h1s[tid*72 + j*8]) = v;
    }
    __syncthreads();

    // ---- L2: [64 pts x 64] @ w2^T -> h2 ----
    short8 w2f[16];
#pragma unroll
    for (int f = 0; f < 16; ++f)
        w2f[f] = *reinterpret_cast<const short8*>(wfrag + ((size_t)f*64 + lane)*8);
    float b2v[8];
#pragma unroll
    for (int n = 0; n < 8; ++n) b2v[n] = b2[n*16 + lm];

#pragma unroll
    for (int t = 0; t < 4; ++t) {
        const int arow = w*64 + t*16 + lm;
        const short8 a0 = *reinterpret_cast<const short8*>(&h1s[arow*72 + lg*8]);
        const short8 a1 = *reinterpret_cast<const short8*>(&h1s[arow*72 + 32 + lg*8]);
        const int wrow = w*64 + t*16 + lg*4;
#pragma unroll
        for (int n = 0; n < 8; ++n) {
            f32x4 acc = {0.f, 0.f, 0.f, 0.f};
            acc = __builtin_amdgcn_mfma_f32_16x16x32_bf16(a0, w2f[n],     acc, 0, 0, 0);
            acc = __builtin_amdgcn_mfma_f32_16x16x32_bf16(a1, w2f[8 + n], acc, 0, 0, 0);
#pragma unroll
            for (int r = 0; r < 4; ++r) {
                const float v = fmaxf(acc[r] + b2v[n], 0.f);
                h2s[(wrow + r)*136 + n*16 + lm] = f2bf(v);
            }
        }
    }
    __syncthreads();

    // ---- L3: [64 pts x 128] @ w3^T, fused maxpool ----
    short8 w3f[32];
#pragma unroll
    for (int f = 0; f < 32; ++f)
        w3f[f] = *reinterpret_cast<const short8*>(wfrag + ((size_t)(16 + f)*64 + lane)*8);

    float pm[8];
#pragma unroll
    for (int n = 0; n < 8; ++n) pm[n] = -3.0e38f;

#pragma unroll
    for (int t = 0; t < 4; ++t) {
        const int arow = w*64 + t*16 + lm;
        const short8 a0 = *reinterpret_cast<const short8*>(&h2s[arow*136 +  0 + lg*8]);
        const short8 a1 = *reinterpret_cast<const short8*>(&h2s[arow*136 + 32 + lg*8]);
        const short8 a2 = *reinterpret_cast<const short8*>(&h2s[arow*136 + 64 + lg*8]);
        const short8 a3 = *reinterpret_cast<const short8*>(&h2s[arow*136 + 96 + lg*8]);
#pragma unroll
        for (int n = 0; n < 8; ++n) {
            f32x4 acc = {0.f, 0.f, 0.f, 0.f};
            acc = __builtin_amdgcn_mfma_f32_16x16x32_bf16(a0, w3f[n],      acc, 0, 0, 0);
            acc = __builtin_amdgcn_mfma_f32_16x16x32_bf16(a1, w3f[8 + n],  acc, 0, 0, 0);
            acc = __builtin_amdgcn_mfma_f32_16x16x32_bf16(a2, w3f[16 + n], acc, 0, 0, 0);
            acc = __builtin_amdgcn_mfma_f32_16x16x32_bf16(a3, w3f[24 + n], acc, 0, 0, 0);
#pragma unroll
            for (int r = 0; r < 4; ++r) pm[n] = fmaxf(pm[n], acc[r]);
        }
    }
#pragma unroll
    for (int n = 0; n < 8; ++n) {
        float v = pm[n];
        v = fmaxf(v, __shfl_xor(v, 16, 64));
        v = fmaxf(v, __shfl_xor(v, 32, 64));
        pm[n] = v;
    }
    if (lg == 0) {
#pragma unroll
        for (int n = 0; n < 8; ++n) wmaxs[w][n*16 + lm] = pm[n];
    }
    __syncthreads();
    if (tid < 128) {
        const float m = fmaxf(fmaxf(wmaxs[0][tid], wmaxs[1][tid]),
                              fmaxf(wmaxs[2][tid], wmaxs[3][tid]));
        hout[(size_t)box*256 + tid] = fmaxf(m + b3[tid], 0.f);
    }
}

// ---------------------------------------------------------------------------
// det motion MLP: 9 -> 64 (relu) -> 128. One block per det.
// ---------------------------------------------------------------------------
__global__ __launch_bounds__(128) void detmlp_kernel(
    const float* __restrict__ boxes,
    const float* __restrict__ w1, const float* __restrict__ b1,
    const float* __restrict__ w2, const float* __restrict__ b2,
    float* __restrict__ hout)
{
    __shared__ float xb[9];
    __shared__ float h1[64];
    const int b = blockIdx.x, t = threadIdx.x;
    if (t < 9) xb[t] = boxes[b*9 + t];
    __syncthreads();
    if (t < 64) {
        float s = b1[t];
#pragma unroll
        for (int c = 0; c < 9; ++c) s = fmaf(w1[t*9+c], xb[c], s);
        h1[t] = fmaxf(s, 0.f);
    }
    __syncthreads();
    float s = b2[t];
    const float* wr = w2 + t*64;
#pragma unroll
    for (int c = 0; c < 64; ++c) s = fmaf(wr[c], h1[c], s);
    hout[(size_t)b * 256 + 128 + t] = s;
}

// ---------------------------------------------------------------------------
__global__ __launch_bounds__(256) void transpose_wih1_kernel(
    const float* __restrict__ in, float* __restrict__ out)
{
    const int id = blockIdx.x * 256 + threadIdx.x;   // 65536 total
    const int k = id >> 9, r = id & 511;
    out[id] = in[r * 128 + k];
}

// ---------------------------------------------------------------------------
// LSTM layer 0: 2 batches/block (256 blocks).
// ---------------------------------------------------------------------------
__global__ __launch_bounds__(512) void lstm_rec0_kernel(
    const float* __restrict__ xseq,
    const float* __restrict__ wih0, const float* __restrict__ whh0,
    const float* __restrict__ b0, float* __restrict__ h0seq)
{
    __shared__ float hs[128][2];
    __shared__ float xb[2][12];
    __shared__ float gs[4][2][128];
    const int r  = threadIdx.x;
    const int b2 = blockIdx.x * 2;
    const int q  = r >> 7 & 3, jj = r & 127;
    const int mb = r >> 7, mj = r & 127;

    float w[128];
#pragma unroll
    for (int k = 0; k < 128; k += 4) {
        const float4 v = *(const float4*)(whh0 + (size_t)r * 128 + k);
        w[k] = v.x; w[k+1] = v.y; w[k+2] = v.z; w[k+3] = v.w;
    }
    float wx[9];
#pragma unroll
    for (int c = 0; c < 9; ++c) wx[c] = wih0[(size_t)r * 9 + c];
    const float bias = b0[r];

    float cst = 0.f;
    if (r < 256) hs[mj][mb] = 0.f;
    __syncthreads();

    for (int t = 0; t < 10; ++t) {
        if (r < 18) xb[r / 9][r % 9] = xseq[((size_t)(b2 + r / 9) * 10 + t) * 9 + r % 9];
        __syncthreads();
        float a0 = bias, a1 = bias;
#pragma unroll
        for (int c = 0; c < 9; ++c) {
            a0 = fmaf(wx[c], xb[0][c], a0);
            a1 = fmaf(wx[c], xb[1][c], a1);
        }
#pragma unroll
        for (int k = 0; k < 128; ++k) {
            const float2 h2 = *(const float2*)&hs[k][0];
            a0 = fmaf(w[k], h2.x, a0);
            a1 = fmaf(w[k], h2.y, a1);
        }
        gs[q][0][jj] = a0;
        gs[q][1][jj] = a1;
        __syncthreads();
        if (r < 256) {
            const float gi = gs[0][mb][mj], gf = gs[1][mb][mj];
            const float gg = gs[2][mb][mj], go = gs[3][mb][mj];
            cst = sigm(gf) * cst + sigm(gi) * tanhf(gg);
            const float hn = sigm(go) * tanhf(cst);
            hs[mj][mb] = hn;
            h0seq[((size_t)(b2 + mb) * 10 + t) * 128 + mj] = hn;
        }
        __syncthreads();
    }
}

// ---------------------------------------------------------------------------
// LSTM layer 1: 2 batches/block (256 blocks).
// ---------------------------------------------------------------------------
__global__ __launch_bounds__(512) void lstm_rec1_kernel(
    const float* __restrict__ h0seq, const float* __restrict__ wih1T,
    const float* __restrict__ whh1, const float* __restrict__ b1,
    float* __restrict__ hout)
{
    __shared__ float hs[128][2];
    __shared__ float xs_[128][2];
    __shared__ float gs[4][2][128];
    const int r  = threadIdx.x;
    const int b2 = blockIdx.x * 2;
    const int q  = r >> 7 & 3, jj = r & 127;
    const int mb = r >> 7, mj = r & 127;

    float w[128];
#pragma unroll
    for (int k = 0; k < 128; k += 4) {
        const float4 v = *(const float4*)(whh1 + (size_t)r * 128 + k);
        w[k] = v.x; w[k+1] = v.y; w[k+2] = v.z; w[k+3] = v.w;
    }
    const float bias = b1[r];

    float cst = 0.f;
    if (r < 256) hs[mj][mb] = 0.f;
    __syncthreads();

    for (int t = 0; t < 10; ++t) {
        if (r < 256)
            xs_[mj][mb] = h0seq[((size_t)(b2 + mb) * 10 + t) * 128 + mj];
        __syncthreads();
        float a0 = bias, a1 = bias;
#pragma unroll
        for (int k = 0; k < 128; ++k) {
            const float wxv = wih1T[k * 512 + r];
            const float2 x2 = *(const float2*)&xs_[k][0];
            const float2 h2 = *(const float2*)&hs[k][0];
            a0 = fmaf(wxv, x2.x, fmaf(w[k], h2.x, a0));
            a1 = fmaf(wxv, x2.y, fmaf(w[k], h2.y, a1));
        }
        gs[q][0][jj] = a0;
        gs[q][1][jj] = a1;
        __syncthreads();
        if (r < 256) {
            const float gi = gs[0][mb][mj], gf = gs[1][mb][mj];
            const float gg = gs[2][mb][mj], go = gs[3][mb][mj];
            cst = sigm(gf) * cst + sigm(gi) * tanhf(gg);
            const float hn = sigm(go) * tanhf(cst);
            hs[mj][mb] = hn;
            if (t == 9)
                hout[(size_t)(N_DET + b2 + mb) * 256 + 128 + mj] = hn;
        }
        __syncthreads();
    }
}

// ---------------------------------------------------------------------------
// EdgeConv GEMM via split-bf16 MFMA (3-product, fp32-grade):
//   C[1024][512] = (hi+lo) @ (Whi+Wlo)^T  ~= hi@Whi + lo@Whi + hi@Wlo
// Grid (32,8), 256 thr = 4 waves; wave: 16 rows x 32 cols. No LDS.
// Epilogue routes to Abuf/Bbuf/phiT/hnext and writes next-layer bf16 shadow.
// ---------------------------------------------------------------------------
__global__ __launch_bounds__(256) void ec_gemm_mfma_kernel(
    const unsigned short* __restrict__ hhi, const unsigned short* __restrict__ hlo,
    const unsigned short* __restrict__ whi, const unsigned short* __restrict__ wlo,
    const float* __restrict__ tb, const float* __restrict__ pb,
    float* __restrict__ Abuf, float* __restrict__ Bbuf,
    float* __restrict__ phiT, float* __restrict__ hnext,
    unsigned short* __restrict__ nhi, unsigned short* __restrict__ nlo)
{
    const int bm = blockIdx.x, bn = blockIdx.y;
    const int tid = threadIdx.x, lane = tid & 63, w = tid >> 6;
    const int lm = lane & 15, lg = lane >> 4;
    const int mrow0 = bm*32 + (w & 1)*16;
    const int nt0   = bn*4 + (w >> 1)*2;      // two n-tiles: nt0, nt0+1
    const int arow  = mrow0 + lm;

    f32x4 acc[2] = {{0.f,0.f,0.f,0.f},{0.f,0.f,0.f,0.f}};

#pragma unroll
    for (int kf = 0; kf < 8; ++kf) {
        const short8 ahi = *reinterpret_cast<const short8*>(
            hhi + (size_t)arow*256 + kf*32 + lg*8);
        const short8 alo = *reinterpret_cast<const short8*>(
            hlo + (size_t)arow*256 + kf*32 + lg*8);
#pragma unroll
        for (int n2 = 0; n2 < 2; ++n2) {
            const size_t foff = ((size_t)((nt0 + n2)*8 + kf)*64 + lane)*8;
            const short8 bhi = *reinterpret_cast<const short8*>(whi + foff);
            const short8 blo = *reinterpret_cast<const short8*>(wlo + foff);
            acc[n2] = __builtin_amdgcn_mfma_f32_16x16x32_bf16(ahi, bhi, acc[n2], 0, 0, 0);
            acc[n2] = __builtin_amdgcn_mfma_f32_16x16x32_bf16(alo, bhi, acc[n2], 0, 0, 0);
            acc[n2] = __builtin_amdgcn_mfma_f32_16x16x32_bf16(ahi, blo, acc[n2], 0, 0, 0);
        }
    }

#pragma unroll
    for (int n2 = 0; n2 < 2; ++n2) {
        const int col = (nt0 + n2)*16 + lm;
#pragma unroll
        for (int r = 0; r < 4; ++r) {
            const int row = mrow0 + lg*4 + r;
            float v = acc[n2][r];
            if (col < 256) {
                if (row < N_DET) Abuf[(size_t)row*256 + col] = v;
                else             Bbuf[(size_t)(row - N_DET)*256 + col] = v;
            } else {
                const int o = col - 256;
                v += pb[o];
                if (row < N_DET) {
                    const float hv = fmaxf(v + tb[o], 0.f);
                    hnext[(size_t)row*256 + o] = hv;
                    const unsigned short hb = f2bf(hv);
                    nhi[(size_t)row*256 + o] = hb;
                    nlo[(size_t)row*256 + o] = f2bf(hv - bf2f(hb));
                } else {
                    phiT[(size_t)(row - N_DET)*256 + o] = v;
                }
            }
        }
    }
}

// ---------------------------------------------------------------------------
// LDS-tiled masked column-max; also writes bf16 shadow of trk rows.
// ---------------------------------------------------------------------------
#define CM_MT 16
#define CM_OT 32
#define CM_NC 64

__global__ __launch_bounds__(256) void ec_colmax_kernel(
    const float* __restrict__ aff,
    const float* __restrict__ Abuf, const float* __restrict__ Bbuf,
    const float* __restrict__ phiT, const float* __restrict__ tb,
    float* __restrict__ hnext,
    unsigned short* __restrict__ nhi, unsigned short* __restrict__ nlo)
{
    __shared__ float As[CM_NC][CM_OT + 4];
    __shared__ float Fs[CM_NC][CM_MT + 4];
    const int t = threadIdx.x;
    const int mtile = blockIdx.x;
    const int otile = blockIdx.y;
    const int mi = t >> 4, oi = t & 15;

    float mx0 = -3.0e38f, mx1 = -3.0e38f;

    for (int n0 = 0; n0 < 512; n0 += CM_NC) {
        if (n0) __syncthreads();
        {
            const int r = t >> 3, c4 = (t & 7) * 4;
#pragma unroll
            for (int rr = 0; rr < 2; ++rr) {
                const float4 v = *(const float4*)(
                    Abuf + (size_t)(n0 + rr*32 + r)*256 + otile*CM_OT + c4);
                *(float4*)&As[rr*32 + r][c4] = v;
            }
        }
        {
            const int n = t >> 2, m4 = (t & 3) * 4;
            const float4 a = *(const float4*)(
                aff + (size_t)(n0 + n)*512 + mtile*CM_MT + m4);
            float4 f;
            f.x = (a.x > 0.f) ? 0.f : -3.0e38f;
            f.y = (a.y > 0.f) ? 0.f : -3.0e38f;
            f.z = (a.z > 0.f) ? 0.f : -3.0e38f;
            f.w = (a.w > 0.f) ? 0.f : -3.0e38f;
            *(float4*)&Fs[n][m4] = f;
        }
        __syncthreads();
#pragma unroll 4
        for (int n = 0; n < CM_NC; ++n) {
            const float f = Fs[n][mi];
            const float2 a = *(const float2*)&As[n][oi*2];
            mx0 = fmaxf(mx0, a.x + f);
            mx1 = fmaxf(mx1, a.y + f);
        }
    }

    const int m = mtile*CM_MT + mi;
    const int o = otile*CM_OT + oi*2;
    const float2 tb2 = *(const float2*)(tb + o);
    const float2 bb  = *(const float2*)(Bbuf + (size_t)m*256 + o);
    const float2 ph  = *(const float2*)(phiT + (size_t)m*256 + o);
    const float v0 = fmaxf(tb2.x, mx0 - bb.x + tb2.x);
    const float v1 = fmaxf(tb2.y, mx1 - bb.y + tb2.y);
    float2 outv;
    outv.x = fmaxf(ph.x + v0, 0.f);
    outv.y = fmaxf(ph.y + v1, 0.f);
    const size_t base = (size_t)(N_DET + m)*256 + o;
    *(float2*)(hnext + base) = outv;
    const unsigned short h0 = f2bf(outv.x), h1 = f2bf(outv.y);
    nhi[base]     = h0;
    nhi[base + 1] = h1;
    nlo[base]     = f2bf(outv.x - bf2f(h0));
    nlo[base + 1] = f2bf(outv.y - bf2f(h1));
}

// ---------------------------------------------------------------------------
// Head projection: P[1024][64] = h @ er_w1^T.
// ---------------------------------------------------------------------------
__global__ __launch_bounds__(256) void headp_kernel(
    const float* __restrict__ h, const float* __restrict__ w1, float* __restrict__ P)
{
    const int tid = threadIdx.x;
    const int o = tid & 63, rl = tid >> 6;
    const int row = blockIdx.x * 4 + rl;
    const float* hr = h + (size_t)row * 256;
    const float* wr = w1 + (size_t)o * 256;
    float s0 = 0.f, s1 = 0.f, s2 = 0.f, s3 = 0.f;
#pragma unroll
    for (int c = 0; c < 256; c += 4) {
        const float4 hv = *(const float4*)(hr + c);
        const float4 wv = *(const float4*)(wr + c);
        s0 = fmaf(hv.x, wv.x, s0);
        s1 = fmaf(hv.y, wv.y, s1);
        s2 = fmaf(hv.z, wv.z, s2);
        s3 = fmaf(hv.w, wv.w, s3);
    }
    P[(size_t)row * 64 + o] = (s0 + s1) + (s2 + s3);
}

// ---------------------------------------------------------------------------
// Pairwise affinity head.
// ---------------------------------------------------------------------------
__global__ __launch_bounds__(256) void pairwise_kernel(
    const float* __restrict__ P, const float* __restrict__ aff,
    const float* __restrict__ eb1, const float* __restrict__ ew2, const float* __restrict__ eb2,
    float* __restrict__ out)
{
    __shared__ float pd[64], sb1[64], sw2[64];
    const int n = blockIdx.y;
    const int t = threadIdx.x;
    if (t < 64)       pd[t]        = P[(size_t)n * 64 + t];
    else if (t < 128) sb1[t - 64]  = eb1[t - 64];
    else if (t < 192) sw2[t - 128] = ew2[t - 128];
    __syncthreads();
    const int m = blockIdx.x * 256 + t;
    const float* pt = P + (size_t)(N_DET + m) * 64;
    float s = eb2[0];
#pragma unroll
    for (int c = 0; c < 64; c += 4) {
        const float4 pv = *(const float4*)(pt + c);
        float e;
        e = fmaxf(pv.x - pd[c+0] + sb1[c+0], 0.f); s = fmaf(e, sw2[c+0], s);
        e = fmaxf(pv.y - pd[c+1] + sb1[c+1], 0.f); s = fmaf(e, sw2[c+1], s);
        e = fmaxf(pv.z - pd[c+2] + sb1[c+2], 0.f); s = fmaf(e, sw2[c+2], s);
        e = fmaxf(pv.w - pd[c+3] + sb1[c+3], 0.f); s = fmaf(e, sw2[c+3], s);
    }
    const float r = 1.f / (1.f + expf(-s));
    const float v = aff[(size_t)n * 512 + m] * r;
    out[(size_t)n * 512 + m] = (v == 0.f) ? 99.f : v;
}

// ---------------------------------------------------------------------------
extern "C" void kernel_launch(void* const* d_in, const int* in_sizes, int n_in,
                              void* d_out, int out_size, void* d_ws, size_t ws_size,
                              hipStream_t stream)
{
    (void)in_sizes; (void)n_in; (void)out_size; (void)ws_size;

    const float* det_pc  = (const float*)d_in[0];
    const float* det_box = (const float*)d_in[1];
    const float* trk_pc  = (const float*)d_in[2];
    const float* trk_box = (const float*)d_in[3];
    const float* aff     = (const float*)d_in[4];
    const float* pn_w1  = (const float*)d_in[6];
    const float* pn_b1  = (const float*)d_in[7];
    const float* pn_w2  = (const float*)d_in[8];
    const float* pn_b2  = (const float*)d_in[9];
    const float* pn_w3  = (const float*)d_in[10];
    const float* pn_b3  = (const float*)d_in[11];
    const float* mlp_w1 = (const float*)d_in[12];
    const float* mlp_b1 = (const float*)d_in[13];
    const float* mlp_w2 = (const float*)d_in[14];
    const float* mlp_b2 = (const float*)d_in[15];
    const float* l0_wih = (const float*)d_in[16];
    const float* l0_whh = (const float*)d_in[17];
    const float* l0_b   = (const float*)d_in[18];
    const float* l1_wih = (const float*)d_in[19];
    const float* l1_whh = (const float*)d_in[20];
    const float* l1_b   = (const float*)d_in[21];
    const float* ec_tw  = (const float*)d_in[22];
    const float* ec_tb  = (const float*)d_in[23];
    const float* ec_pw  = (const float*)d_in[24];
    const float* ec_pb  = (const float*)d_in[25];
    const float* er_w1  = (const float*)d_in[26];
    const float* er_b1  = (const float*)d_in[27];
    const float* er_w2  = (const float*)d_in[28];
    const float* er_b2  = (const float*)d_in[29];

    float* ws    = (float*)d_ws;
    float* hA    = ws;                    // [1024][256]
    float* hB    = hA + 1024*256;         // [1024][256]
    float* Abuf  = hB + 1024*256;         // [512][256]
    float* Bbuf  = Abuf + 512*256;        // [512][256]
    float* phiT  = Bbuf + 512*256;        // [512][256]
    float* P     = phiT + 512*256;        // [1024][64]
    float* h0seq = P + 1024*64;           // [512][10][128]
    float* wih1T = h0seq + 512*10*128;    // [128][512]
    unsigned short* wfrag = (unsigned short*)(wih1T + 128*512);  // 48*64*8
    unsigned short* ecwhi = wfrag + 48*64*8;                     // 1024*64*8
    unsigned short* ecwlo = ecwhi + 1024*64*8;                   // 1024*64*8
    unsigned short* hbfA_hi = ecwlo + 1024*64*8;                 // 1024*256
    unsigned short* hbfA_lo = hbfA_hi + 1024*256;
    unsigned short* hbfB_hi = hbfA_lo + 1024*256;
    unsigned short* hbfB_lo = hbfB_hi + 1024*256;
    // total ~11 MB

    pn_wprep_kernel<<<48, 64, 0, stream>>>(pn_w2, pn_w3, wfrag);
    ec_wprep_kernel<<<1024, 64, 0, stream>>>(ec_tw, ec_pw, ecwhi, ecwlo);
    pointnet_mfma_kernel<<<1024, 256, 0, stream>>>(det_pc, trk_pc, pn_w1, pn_b1,
                                                   wfrag, pn_b2, pn_b3, hA);
    detmlp_kernel<<<512, 128, 0, stream>>>(det_box, mlp_w1, mlp_b1, mlp_w2, mlp_b2, hA);
    transpose_wih1_kernel<<<256, 256, 0, stream>>>(l1_wih, wih1T);
    lstm_rec0_kernel<<<256, 512, 0, stream>>>(trk_box, l0_wih, l0_whh, l0_b, h0seq);
    lstm_rec1_kernel<<<256, 512, 0, stream>>>(h0seq, wih1T, l1_whh, l1_b, hA);
    h2bf_kernel<<<256, 256, 0, stream>>>(hA, hbfA_hi, hbfA_lo);

    float* hcur = hA;  float* hnext = hB;
    unsigned short* chi = hbfA_hi; unsigned short* clo = hbfA_lo;
    unsigned short* nhi = hbfB_hi; unsigned short* nlo = hbfB_lo;
    for (int k = 0; k < 4; ++k) {
        const float* tb = ec_tb + (size_t)k * 256;
        const float* pb = ec_pb + (size_t)k * 256;
        ec_gemm_mfma_kernel<<<dim3(32, 8), 256, 0, stream>>>(
            chi, clo, ecwhi + (size_t)k*256*64*8, ecwlo + (size_t)k*256*64*8,
            tb, pb, Abuf, Bbuf, phiT, hnext, nhi, nlo);
        ec_colmax_kernel<<<dim3(32, 8), 256, 0, stream>>>(aff, Abuf, Bbuf, phiT, tb,
                                                          hnext, nhi, nlo);
        float* tf = hcur; hcur = hnext; hnext = tf;
        unsigned short* th = chi; chi = nhi; nhi = th;
        unsigned short* tl = clo; clo = nlo; nlo = tl;
    }

    headp_kernel<<<256, 256, 0, stream>>>(hcur, er_w1, P);
    pairwise_kernel<<<dim3(2, 512), 256, 0, stream>>>(P, aff, er_b1, er_w2, er_b2,
                                                      (float*)d_out);
}

// Round 7
// 349.257 us; speedup vs baseline: 12.1096x; 1.0950x over previous
//
#include <hip/hip_runtime.h>
#include <math.h>

#define N_DET 512
#define N_TRK 512
#define NPTS  256

typedef __attribute__((ext_vector_type(8))) short short8;
typedef __attribute__((ext_vector_type(4))) float f32x4;
typedef unsigned short ushort_t;

__device__ __forceinline__ float sigm(float x) { return 1.f / (1.f + expf(-x)); }

__device__ __forceinline__ unsigned short f2bf(float f) {
    unsigned u = __float_as_uint(f);
    u += 0x7FFF + ((u >> 16) & 1);          // round-to-nearest-even
    return (unsigned short)(u >> 16);
}
__device__ __forceinline__ float bf2f(unsigned short h) {
    return __uint_as_float(((unsigned)h) << 16);
}

// ---------------------------------------------------------------------------
// Pack pointnet w2/w3 into MFMA B-fragment-major bf16.
// ---------------------------------------------------------------------------
__global__ __launch_bounds__(64) void pn_wprep_kernel(
    const float* __restrict__ w2, const float* __restrict__ w3,
    unsigned short* __restrict__ wfrag)
{
    const int f = blockIdx.x;          // 48
    const int lane = threadIdx.x;      // 64
    const int lm = lane & 15, lg = lane >> 4;
    const float* src;
    if (f < 16) {
        const int s = f >> 3, n = f & 7;
        src = w2 + (size_t)(n*16 + lm)*64 + s*32 + lg*8;
    } else {
        const int f2 = f - 16, s = f2 >> 3, n = f2 & 7;
        src = w3 + (size_t)(n*16 + lm)*128 + s*32 + lg*8;
    }
    short8 v;
#pragma unroll
    for (int j = 0; j < 8; ++j) v[j] = (short)f2bf(src[j]);
    *reinterpret_cast<short8*>(wfrag + ((size_t)f*64 + lane)*8) = v;
}

// ---------------------------------------------------------------------------
// Pack EdgeConv W=[tw;pw] (per layer, [512][256]) into frag-major bf16 hi/lo.
// ---------------------------------------------------------------------------
__global__ __launch_bounds__(64) void ec_wprep_kernel(
    const float* __restrict__ tw, const float* __restrict__ pw,
    unsigned short* __restrict__ whi, unsigned short* __restrict__ wlo)
{
    const int id = blockIdx.x;                 // 1024 = 4 layers * 32 ntiles * 8 kf
    const int layer = id >> 8;
    const int ntile = (id >> 3) & 31, kf = id & 7;
    const int lane = threadIdx.x;
    const int lm = lane & 15, lg = lane >> 4;
    const int col = ntile*16 + lm, k = kf*32 + lg*8;
    const float* src = (col < 256)
        ? tw + ((size_t)layer*256 + col)*256 + k
        : pw + ((size_t)layer*256 + (col - 256))*256 + k;
    short8 hi, lo;
#pragma unroll
    for (int j = 0; j < 8; ++j) {
        const float f = src[j];
        const unsigned short h = f2bf(f);
        hi[j] = (short)h;
        lo[j] = (short)f2bf(f - bf2f(h));
    }
    const size_t off = ((size_t)id*64 + lane)*8;
    *reinterpret_cast<short8*>(whi + off) = hi;
    *reinterpret_cast<short8*>(wlo + off) = lo;
}

// ---------------------------------------------------------------------------
// Pack LSTM whh0 / wih1 / whh1 ([512][128] each) into B-frag bf16 (hi only).
// frag id = mat*128 + nt*4 + kf; lane: W[nt*16+(l&15)][kf*32+(l>>4)*8+j]
// ---------------------------------------------------------------------------
__global__ __launch_bounds__(64) void lstm_wprep_kernel(
    const float* __restrict__ whh0, const float* __restrict__ wih1,
    const float* __restrict__ whh1, unsigned short* __restrict__ wf)
{
    const int id = blockIdx.x;                  // 384
    const int mat = id >> 7, rest = id & 127;
    const int nt = rest >> 2, kf = rest & 3;
    const int lane = threadIdx.x;
    const int lm = lane & 15, lg = lane >> 4;
    const float* src = (mat == 0) ? whh0 : ((mat == 1) ? wih1 : whh1);
    const float* p = src + (size_t)(nt*16 + lm)*128 + kf*32 + lg*8;
    short8 v;
#pragma unroll
    for (int j = 0; j < 8; ++j) v[j] = (short)f2bf(p[j]);
    *reinterpret_cast<short8*>(wf + ((size_t)id*64 + lane)*8) = v;
}

// ---------------------------------------------------------------------------
// xg0[bt][512] = xseq[bt][9] @ wih0^T  (no bias; bias added in mixer)
// ---------------------------------------------------------------------------
__global__ __launch_bounds__(512) void lstm_xg0_kernel(
    const float* __restrict__ xseq, const float* __restrict__ wih0,
    float* __restrict__ xg0)
{
    __shared__ float xs[8][12];
    const int tid = threadIdx.x;
    const int m0 = blockIdx.x * 8;              // grid 640
    if (tid < 72) xs[tid / 9][tid % 9] = xseq[(size_t)m0*9 + tid];
    float wx[9];
#pragma unroll
    for (int c = 0; c < 9; ++c) wx[c] = wih0[tid*9 + c];
    __syncthreads();
#pragma unroll
    for (int i = 0; i < 8; ++i) {
        float s = 0.f;
#pragma unroll
        for (int c = 0; c < 9; ++c) s = fmaf(wx[c], xs[i][c], s);
        xg0[(size_t)(m0 + i)*512 + tid] = s;
    }
}

// ---------------------------------------------------------------------------
// xg1[bt][512] = h0seq[bt][128] @ wih1^T via split-bf16 MFMA (h hi+lo).
// grid (80, 8), 256 thr = 4 waves, wave = 16 rows x 64 cols.
// ---------------------------------------------------------------------------
__global__ __launch_bounds__(256) void lstm_xg1_kernel(
    const unsigned short* __restrict__ h0hi, const unsigned short* __restrict__ h0lo,
    const unsigned short* __restrict__ wfrag, float* __restrict__ xg1)
{
    const int tid = threadIdx.x, lane = tid & 63, w = tid >> 6;
    const int lm = lane & 15, lg = lane >> 4;
    const int m0 = blockIdx.x*64 + w*16;
    const int bn = blockIdx.y;
    const int arow = m0 + lm;
    short8 ahi[4], alo[4];
#pragma unroll
    for (int kf = 0; kf < 4; ++kf) {
        ahi[kf] = *reinterpret_cast<const short8*>(h0hi + (size_t)arow*128 + kf*32 + lg*8);
        alo[kf] = *reinterpret_cast<const short8*>(h0lo + (size_t)arow*128 + kf*32 + lg*8);
    }
#pragma unroll
    for (int nt = 0; nt < 4; ++nt) {
        f32x4 acc = {0.f, 0.f, 0.f, 0.f};
#pragma unroll
        for (int kf = 0; kf < 4; ++kf) {
            const short8 bf = *reinterpret_cast<const short8*>(
                wfrag + ((size_t)((bn*4 + nt)*4 + kf)*64 + lane)*8);
            acc = __builtin_amdgcn_mfma_f32_16x16x32_bf16(ahi[kf], bf, acc, 0, 0, 0);
            acc = __builtin_amdgcn_mfma_f32_16x16x32_bf16(alo[kf], bf, acc, 0, 0, 0);
        }
#pragma unroll
        for (int r = 0; r < 4; ++r)
            xg1[(size_t)(m0 + lg*4 + r)*512 + bn*64 + nt*16 + lm] = acc[r];
    }
}

// ---------------------------------------------------------------------------
// LSTM recurrent step kernel (MFMA). 32 blocks x 512 thr, 16 batches/block.
// whh bf16 frags in VGPRs (loaded once); h state split-bf16 in LDS frag
// layout; gate mix via LDS transpose. xg = precomputed non-recurrent part.
// LAYER 0: writes h0seq hi/lo every step. LAYER 1: writes final h at t=9.
// ---------------------------------------------------------------------------
template<int LAYER>
__global__ __launch_bounds__(512, 2) void lstm_mfma_kernel(
    const unsigned short* __restrict__ wfrag,
    const float* __restrict__ xg, const float* __restrict__ bias,
    unsigned short* __restrict__ h0hi, unsigned short* __restrict__ h0lo,
    float* __restrict__ hout)
{
    __shared__ unsigned short hfhi[4*64*8];     // A-frag layout, 4 KB
    __shared__ unsigned short hflo[4*64*8];
    __shared__ float gs[512*20];                // [gate][batch(16)+pad4], 40 KB

    const int tid = threadIdx.x;
    const int lane = tid & 63, w = tid >> 6;
    const int lm = lane & 15, lg = lane >> 4;
    const int b0 = blockIdx.x * 16;

    // weight fragments -> VGPRs (wave w owns gates w*64 .. w*64+63)
    short8 wf[4][4];
#pragma unroll
    for (int nt = 0; nt < 4; ++nt)
#pragma unroll
        for (int kf = 0; kf < 4; ++kf)
            wf[nt][kf] = *reinterpret_cast<const short8*>(
                wfrag + ((size_t)((w*4 + nt)*4 + kf)*64 + lane)*8);

    for (int i = tid; i < 2048; i += 512) { hfhi[i] = 0; hflo[i] = 0; }

    // mixer constants: unit mj, batches mb0..mb0+3
    const int mj = tid & 127;
    const int mb0 = (tid >> 7) * 4;
    const float bi = bias[mj], bf_ = bias[128 + mj];
    const float bg = bias[256 + mj], bo = bias[384 + mj];
    const int hkf = mj >> 5, hlg = (mj >> 3) & 3, hjj = mj & 7;
    float c[4] = {0.f, 0.f, 0.f, 0.f};

    __syncthreads();

    for (int t = 0; t < 10; ++t) {
        // prefetch non-recurrent gate parts (independent of this step's MFMA)
        float xgv[4][4];
#pragma unroll
        for (int s = 0; s < 4; ++s) {
            const size_t btg = ((size_t)(b0 + mb0 + s)*10 + t)*512;
            xgv[s][0] = xg[btg + mj];
            xgv[s][1] = xg[btg + 128 + mj];
            xgv[s][2] = xg[btg + 256 + mj];
            xgv[s][3] = xg[btg + 384 + mj];
        }
        // recurrent part: G = H @ whh^T (split-bf16 A, bf16 B)
        short8 ahi[4], alo[4];
#pragma unroll
        for (int kf = 0; kf < 4; ++kf) {
            ahi[kf] = *reinterpret_cast<const short8*>(&hfhi[(kf*64 + lane)*8]);
            alo[kf] = *reinterpret_cast<const short8*>(&hflo[(kf*64 + lane)*8]);
        }
#pragma unroll
        for (int nt = 0; nt < 4; ++nt) {
            f32x4 acc = {0.f, 0.f, 0.f, 0.f};
#pragma unroll
            for (int kf = 0; kf < 4; ++kf) {
                acc = __builtin_amdgcn_mfma_f32_16x16x32_bf16(ahi[kf], wf[nt][kf], acc, 0, 0, 0);
                acc = __builtin_amdgcn_mfma_f32_16x16x32_bf16(alo[kf], wf[nt][kf], acc, 0, 0, 0);
            }
            const int g = w*64 + nt*16 + lm;
            float4 tmp; tmp.x = acc[0]; tmp.y = acc[1]; tmp.z = acc[2]; tmp.w = acc[3];
            *(float4*)&gs[g*20 + lg*4] = tmp;    // batches lg*4..lg*4+3
        }
        __syncthreads();
        // gate mix
#pragma unroll
        for (int s = 0; s < 4; ++s) {
            const int b = mb0 + s;
            const float gi = gs[mj*20 + b]         + xgv[s][0] + bi;
            const float gf = gs[(128 + mj)*20 + b] + xgv[s][1] + bf_;
            const float gg = gs[(256 + mj)*20 + b] + xgv[s][2] + bg;
            const float go = gs[(384 + mj)*20 + b] + xgv[s][3] + bo;
            c[s] = sigm(gf)*c[s] + sigm(gi)*tanhf(gg);
            const float hn = sigm(go)*tanhf(c[s]);
            const unsigned short hh = f2bf(hn);
            const unsigned short hl = f2bf(hn - bf2f(hh));
            hfhi[(hkf*64 + hlg*16 + b)*8 + hjj] = hh;
            hflo[(hkf*64 + hlg*16 + b)*8 + hjj] = hl;
            if constexpr (LAYER == 0) {
                h0hi[((size_t)(b0 + b)*10 + t)*128 + mj] = hh;
                h0lo[((size_t)(b0 + b)*10 + t)*128 + mj] = hl;
            } else {
                if (t == 9)
                    hout[(size_t)(N_DET + b0 + b)*256 + 128 + mj] = hn;
            }
        }
        __syncthreads();
    }
}

// ---------------------------------------------------------------------------
// h (fp32 [1024][256]) -> split-bf16 shadow (hi, lo).
// ---------------------------------------------------------------------------
__global__ __launch_bounds__(256) void h2bf_kernel(
    const float* __restrict__ h,
    unsigned short* __restrict__ hi, unsigned short* __restrict__ lo)
{
    const int id = blockIdx.x * 256 + threadIdx.x;   // 65536, 4 elems each
    const float4 v = *(const float4*)(h + (size_t)id*4);
    ushort_t h4[4], l4[4];
    const float vv[4] = {v.x, v.y, v.z, v.w};
#pragma unroll
    for (int j = 0; j < 4; ++j) {
        h4[j] = f2bf(vv[j]);
        l4[j] = f2bf(vv[j] - bf2f(h4[j]));
    }
    *(ulong1*)(hi + (size_t)id*4) = *(ulong1*)h4;
    *(ulong1*)(lo + (size_t)id*4) = *(ulong1*)l4;
}

// ---------------------------------------------------------------------------
// PointNet fused MFMA kernel: one box per block, 256 threads (4 waves).
// ---------------------------------------------------------------------------
__global__ __launch_bounds__(256, 1) void pointnet_mfma_kernel(
    const float* __restrict__ det_pc, const float* __restrict__ trk_pc,
    const float* __restrict__ w1, const float* __restrict__ b1,
    const unsigned short* __restrict__ wfrag,
    const float* __restrict__ b2, const float* __restrict__ b3,
    float* __restrict__ hout)
{
    __shared__ unsigned short h1s[256*72];
    __shared__ unsigned short h2s[256*136];
    __shared__ float wmaxs[4][128];

    const int tid = threadIdx.x;
    const int box = blockIdx.x;
    const int lane = tid & 63, w = tid >> 6;
    const int lm = lane & 15, lg = lane >> 4;

    // ---- L1: thread = point ----
    const float* pc = (box < N_DET) ? det_pc + ((size_t)box*NPTS + tid)*3
                                    : trk_pc + ((size_t)(box - N_DET)*NPTS + tid)*3;
    const float x = pc[0], y = pc[1], z = pc[2];
#pragma unroll
    for (int j = 0; j < 8; ++j) {
        short8 v;
#pragma unroll
        for (int o = 0; o < 8; ++o) {
            const int ch = j*8 + o;
            float s = fmaf(w1[ch*3+0], x, fmaf(w1[ch*3+1], y,
                        fmaf(w1[ch*3+2], z, b1[ch])));
            v[o] = (short)f2bf(fmaxf(s, 0.f));
        }
        *reinterpret_cast<short8*>(&h1s[tid*72 + j*8]) = v;
    }
    __syncthreads();

    // ---- L2: [64 pts x 64] @ w2^T -> h2 ----
    short8 w2f[16];
#pragma unroll
    for (int f = 0; f < 16; ++f)
        w2f[f] = *reinterpret_cast<const short8*>(wfrag + ((size_t)f*64 + lane)*8);
    float b2v[8];
#pragma unroll
    for (int n = 0; n < 8; ++n) b2v[n] = b2[n*16 + lm];

#pragma unroll
    for (int t = 0; t < 4; ++t) {
        const int arow = w*64 + t*16 + lm;
        const short8 a0 = *reinterpret_cast<const short8*>(&h1s[arow*72 + lg*8]);
        const short8 a1 = *reinterpret_cast<const short8*>(&h1s[arow*72 + 32 + lg*8]);
        const int wrow = w*64 + t*16 + lg*4;
#pragma unroll
        for (int n = 0; n < 8; ++n) {
            f32x4 acc = {0.f, 0.f, 0.f, 0.f};
            acc = __builtin_amdgcn_mfma_f32_16x16x32_bf16(a0, w2f[n],     acc, 0, 0, 0);
            acc = __builtin_amdgcn_mfma_f32_16x16x32_bf16(a1, w2f[8 + n], acc, 0, 0, 0);
#pragma unroll
            for (int r = 0; r < 4; ++r) {
                const float v = fmaxf(acc[r] + b2v[n], 0.f);
                h2s[(wrow + r)*136 + n*16 + lm] = f2bf(v);
            }
        }
    }
    __syncthreads();

    // ---- L3: [64 pts x 128] @ w3^T, fused maxpool ----
    short8 w3f[32];
#pragma unroll
    for (int f = 0; f < 32; ++f)
        w3f[f] = *reinterpret_cast<const short8*>(wfrag + ((size_t)(16 + f)*64 + lane)*8);

    float pm[8];
#pragma unroll
    for (int n = 0; n < 8; ++n) pm[n] = -3.0e38f;

#pragma unroll
    for (int t = 0; t < 4; ++t) {
        const int arow = w*64 + t*16 + lm;
        const short8 a0 = *reinterpret_cast<const short8*>(&h2s[arow*136 +  0 + lg*8]);
        const short8 a1 = *reinterpret_cast<const short8*>(&h2s[arow*136 + 32 + lg*8]);
        const short8 a2 = *reinterpret_cast<const short8*>(&h2s[arow*136 + 64 + lg*8]);
        const short8 a3 = *reinterpret_cast<const short8*>(&h2s[arow*136 + 96 + lg*8]);
#pragma unroll
        for (int n = 0; n < 8; ++n) {
            f32x4 acc = {0.f, 0.f, 0.f, 0.f};
            acc = __builtin_amdgcn_mfma_f32_16x16x32_bf16(a0, w3f[n],      acc, 0, 0, 0);
            acc = __builtin_amdgcn_mfma_f32_16x16x32_bf16(a1, w3f[8 + n],  acc, 0, 0, 0);
            acc = __builtin_amdgcn_mfma_f32_16x16x32_bf16(a2, w3f[16 + n], acc, 0, 0, 0);
            acc = __builtin_amdgcn_mfma_f32_16x16x32_bf16(a3, w3f[24 + n], acc, 0, 0, 0);
#pragma unroll
            for (int r = 0; r < 4; ++r) pm[n] = fmaxf(pm[n], acc[r]);
        }
    }
#pragma unroll
    for (int n = 0; n < 8; ++n) {
        float v = pm[n];
        v = fmaxf(v, __shfl_xor(v, 16, 64));
        v = fmaxf(v, __shfl_xor(v, 32, 64));
        pm[n] = v;
    }
    if (lg == 0) {
#pragma unroll
        for (int n = 0; n < 8; ++n) wmaxs[w][n*16 + lm] = pm[n];
    }
    __syncthreads();
    if (tid < 128) {
        const float m = fmaxf(fmaxf(wmaxs[0][tid], wmaxs[1][tid]),
                              fmaxf(wmaxs[2][tid], wmaxs[3][tid]));
        hout[(size_t)box*256 + tid] = fmaxf(m + b3[tid], 0.f);
    }
}

// ---------------------------------------------------------------------------
// det motion MLP: 9 -> 64 (relu) -> 128. One block per det.
// ---------------------------------------------------------------------------
__global__ __launch_bounds__(128) void detmlp_kernel(
    const float* __restrict__ boxes,
    const float* __restrict__ w1, const float* __restrict__ b1,
    const float* __restrict__ w2, const float* __restrict__ b2,
    float* __restrict__ hout)
{
    __shared__ float xb[9];
    __shared__ float h1[64];
    const int b = blockIdx.x, t = threadIdx.x;
    if (t < 9) xb[t] = boxes[b*9 + t];
    __syncthreads();
    if (t < 64) {
        float s = b1[t];
#pragma unroll
        for (int c = 0; c < 9; ++c) s = fmaf(w1[t*9+c], xb[c], s);
        h1[t] = fmaxf(s, 0.f);
    }
    __syncthreads();
    float s = b2[t];
    const float* wr = w2 + t*64;
#pragma unroll
    for (int c = 0; c < 64; ++c) s = fmaf(wr[c], h1[c], s);
    hout[(size_t)b * 256 + 128 + t] = s;
}

// ---------------------------------------------------------------------------
// EdgeConv GEMM via split-bf16 MFMA (3-product, fp32-grade).
// ---------------------------------------------------------------------------
__global__ __launch_bounds__(256) void ec_gemm_mfma_kernel(
    const unsigned short* __restrict__ hhi, const unsigned short* __restrict__ hlo,
    const unsigned short* __restrict__ whi, const unsigned short* __restrict__ wlo,
    const float* __restrict__ tb, const float* __restrict__ pb,
    float* __restrict__ Abuf, float* __restrict__ Bbuf,
    float* __restrict__ phiT, float* __restrict__ hnext,
    unsigned short* __restrict__ nhi, unsigned short* __restrict__ nlo)
{
    const int bm = blockIdx.x, bn = blockIdx.y;
    const int tid = threadIdx.x, lane = tid & 63, w = tid >> 6;
    const int lm = lane & 15, lg = lane >> 4;
    const int mrow0 = bm*32 + (w & 1)*16;
    const int nt0   = bn*4 + (w >> 1)*2;
    const int arow  = mrow0 + lm;

    f32x4 acc[2] = {{0.f,0.f,0.f,0.f},{0.f,0.f,0.f,0.f}};

#pragma unroll
    for (int kf = 0; kf < 8; ++kf) {
        const short8 ahi = *reinterpret_cast<const short8*>(
            hhi + (size_t)arow*256 + kf*32 + lg*8);
        const short8 alo = *reinterpret_cast<const short8*>(
            hlo + (size_t)arow*256 + kf*32 + lg*8);
#pragma unroll
        for (int n2 = 0; n2 < 2; ++n2) {
            const size_t foff = ((size_t)((nt0 + n2)*8 + kf)*64 + lane)*8;
            const short8 bhi = *reinterpret_cast<const short8*>(whi + foff);
            const short8 blo = *reinterpret_cast<const short8*>(wlo + foff);
            acc[n2] = __builtin_amdgcn_mfma_f32_16x16x32_bf16(ahi, bhi, acc[n2], 0, 0, 0);
            acc[n2] = __builtin_amdgcn_mfma_f32_16x16x32_bf16(alo, bhi, acc[n2], 0, 0, 0);
            acc[n2] = __builtin_amdgcn_mfma_f32_16x16x32_bf16(ahi, blo, acc[n2], 0, 0, 0);
        }
    }

#pragma unroll
    for (int n2 = 0; n2 < 2; ++n2) {
        const int col = (nt0 + n2)*16 + lm;
#pragma unroll
        for (int r = 0; r < 4; ++r) {
            const int row = mrow0 + lg*4 + r;
            float v = acc[n2][r];
            if (col < 256) {
                if (row < N_DET) Abuf[(size_t)row*256 + col] = v;
                else             Bbuf[(size_t)(row - N_DET)*256 + col] = v;
            } else {
                const int o = col - 256;
                v += pb[o];
                if (row < N_DET) {
                    const float hv = fmaxf(v + tb[o], 0.f);
                    hnext[(size_t)row*256 + o] = hv;
                    const unsigned short hb = f2bf(hv);
                    nhi[(size_t)row*256 + o] = hb;
                    nlo[(size_t)row*256 + o] = f2bf(hv - bf2f(hb));
                } else {
                    phiT[(size_t)(row - N_DET)*256 + o] = v;
                }
            }
        }
    }
}

// ---------------------------------------------------------------------------
// LDS-tiled masked column-max; also writes bf16 shadow of trk rows.
// ---------------------------------------------------------------------------
#define CM_MT 16
#define CM_OT 32
#define CM_NC 64

__global__ __launch_bounds__(256) void ec_colmax_kernel(
    const float* __restrict__ aff,
    const float* __restrict__ Abuf, const float* __restrict__ Bbuf,
    const float* __restrict__ phiT, const float* __restrict__ tb,
    float* __restrict__ hnext,
    unsigned short* __restrict__ nhi, unsigned short* __restrict__ nlo)
{
    __shared__ float As[CM_NC][CM_OT + 4];
    __shared__ float Fs[CM_NC][CM_MT + 4];
    const int t = threadIdx.x;
    const int mtile = blockIdx.x;
    const int otile = blockIdx.y;
    const int mi = t >> 4, oi = t & 15;

    float mx0 = -3.0e38f, mx1 = -3.0e38f;

    for (int n0 = 0; n0 < 512; n0 += CM_NC) {
        if (n0) __syncthreads();
        {
            const int r = t >> 3, c4 = (t & 7) * 4;
#pragma unroll
            for (int rr = 0; rr < 2; ++rr) {
                const float4 v = *(const float4*)(
                    Abuf + (size_t)(n0 + rr*32 + r)*256 + otile*CM_OT + c4);
                *(float4*)&As[rr*32 + r][c4] = v;
            }
        }
        {
            const int n = t >> 2, m4 = (t & 3) * 4;
            const float4 a = *(const float4*)(
                aff + (size_t)(n0 + n)*512 + mtile*CM_MT + m4);
            float4 f;
            f.x = (a.x > 0.f) ? 0.f : -3.0e38f;
            f.y = (a.y > 0.f) ? 0.f : -3.0e38f;
            f.z = (a.z > 0.f) ? 0.f : -3.0e38f;
            f.w = (a.w > 0.f) ? 0.f : -3.0e38f;
            *(float4*)&Fs[n][m4] = f;
        }
        __syncthreads();
#pragma unroll 4
        for (int n = 0; n < CM_NC; ++n) {
            const float f = Fs[n][mi];
            const float2 a = *(const float2*)&As[n][oi*2];
            mx0 = fmaxf(mx0, a.x + f);
            mx1 = fmaxf(mx1, a.y + f);
        }
    }

    const int m = mtile*CM_MT + mi;
    const int o = otile*CM_OT + oi*2;
    const float2 tb2 = *(const float2*)(tb + o);
    const float2 bb  = *(const float2*)(Bbuf + (size_t)m*256 + o);
    const float2 ph  = *(const float2*)(phiT + (size_t)m*256 + o);
    const float v0 = fmaxf(tb2.x, mx0 - bb.x + tb2.x);
    const float v1 = fmaxf(tb2.y, mx1 - bb.y + tb2.y);
    float2 outv;
    outv.x = fmaxf(ph.x + v0, 0.f);
    outv.y = fmaxf(ph.y + v1, 0.f);
    const size_t base = (size_t)(N_DET + m)*256 + o;
    *(float2*)(hnext + base) = outv;
    const unsigned short h0 = f2bf(outv.x), h1 = f2bf(outv.y);
    nhi[base]     = h0;
    nhi[base + 1] = h1;
    nlo[base]     = f2bf(outv.x - bf2f(h0));
    nlo[base + 1] = f2bf(outv.y - bf2f(h1));
}

// ---------------------------------------------------------------------------
// Head projection: P[1024][64] = h @ er_w1^T.
// ---------------------------------------------------------------------------
__global__ __launch_bounds__(256) void headp_kernel(
    const float* __restrict__ h, const float* __restrict__ w1, float* __restrict__ P)
{
    const int tid = threadIdx.x;
    const int o = tid & 63, rl = tid >> 6;
    const int row = blockIdx.x * 4 + rl;
    const float* hr = h + (size_t)row * 256;
    const float* wr = w1 + (size_t)o * 256;
    float s0 = 0.f, s1 = 0.f, s2 = 0.f, s3 = 0.f;
#pragma unroll
    for (int c = 0; c < 256; c += 4) {
        const float4 hv = *(const float4*)(hr + c);
        const float4 wv = *(const float4*)(wr + c);
        s0 = fmaf(hv.x, wv.x, s0);
        s1 = fmaf(hv.y, wv.y, s1);
        s2 = fmaf(hv.z, wv.z, s2);
        s3 = fmaf(hv.w, wv.w, s3);
    }
    P[(size_t)row * 64 + o] = (s0 + s1) + (s2 + s3);
}

// ---------------------------------------------------------------------------
// Pairwise affinity head.
// ---------------------------------------------------------------------------
__global__ __launch_bounds__(256) void pairwise_kernel(
    const float* __restrict__ P, const float* __restrict__ aff,
    const float* __restrict__ eb1, const float* __restrict__ ew2, const float* __restrict__ eb2,
    float* __restrict__ out)
{
    __shared__ float pd[64], sb1[64], sw2[64];
    const int n = blockIdx.y;
    const int t = threadIdx.x;
    if (t < 64)       pd[t]        = P[(size_t)n * 64 + t];
    else if (t < 128) sb1[t - 64]  = eb1[t - 64];
    else if (t < 192) sw2[t - 128] = ew2[t - 128];
    __syncthreads();
    const int m = blockIdx.x * 256 + t;
    const float* pt = P + (size_t)(N_DET + m) * 64;
    float s = eb2[0];
#pragma unroll
    for (int c = 0; c < 64; c += 4) {
        const float4 pv = *(const float4*)(pt + c);
        float e;
        e = fmaxf(pv.x - pd[c+0] + sb1[c+0], 0.f); s = fmaf(e, sw2[c+0], s);
        e = fmaxf(pv.y - pd[c+1] + sb1[c+1], 0.f); s = fmaf(e, sw2[c+1], s);
        e = fmaxf(pv.z - pd[c+2] + sb1[c+2], 0.f); s = fmaf(e, sw2[c+2], s);
        e = fmaxf(pv.w - pd[c+3] + sb1[c+3], 0.f); s = fmaf(e, sw2[c+3], s);
    }
    const float r = 1.f / (1.f + expf(-s));
    const float v = aff[(size_t)n * 512 + m] * r;
    out[(size_t)n * 512 + m] = (v == 0.f) ? 99.f : v;
}

// ---------------------------------------------------------------------------
extern "C" void kernel_launch(void* const* d_in, const int* in_sizes, int n_in,
                              void* d_out, int out_size, void* d_ws, size_t ws_size,
                              hipStream_t stream)
{
    (void)in_sizes; (void)n_in; (void)out_size; (void)ws_size;

    const float* det_pc  = (const float*)d_in[0];
    const float* det_box = (const float*)d_in[1];
    const float* trk_pc  = (const float*)d_in[2];
    const float* trk_box = (const float*)d_in[3];
    const float* aff     = (const float*)d_in[4];
    const float* pn_w1  = (const float*)d_in[6];
    const float* pn_b1  = (const float*)d_in[7];
    const float* pn_w2  = (const float*)d_in[8];
    const float* pn_b2  = (const float*)d_in[9];
    const float* pn_w3  = (const float*)d_in[10];
    const float* pn_b3  = (const float*)d_in[11];
    const float* mlp_w1 = (const float*)d_in[12];
    const float* mlp_b1 = (const float*)d_in[13];
    const float* mlp_w2 = (const float*)d_in[14];
    const float* mlp_b2 = (const float*)d_in[15];
    const float* l0_wih = (const float*)d_in[16];
    const float* l0_whh = (const float*)d_in[17];
    const float* l0_b   = (const float*)d_in[18];
    const float* l1_wih = (const float*)d_in[19];
    const float* l1_whh = (const float*)d_in[20];
    const float* l1_b   = (const float*)d_in[21];
    const float* ec_tw  = (const float*)d_in[22];
    const float* ec_tb  = (const float*)d_in[23];
    const float* ec_pw  = (const float*)d_in[24];
    const float* ec_pb  = (const float*)d_in[25];
    const float* er_w1  = (const float*)d_in[26];
    const float* er_b1  = (const float*)d_in[27];
    const float* er_w2  = (const float*)d_in[28];
    const float* er_b2  = (const float*)d_in[29];

    float* ws    = (float*)d_ws;
    float* hA    = ws;                    // [1024][256]
    float* hB    = hA + 1024*256;         // [1024][256]
    float* Abuf  = hB + 1024*256;         // [512][256]
    float* Bbuf  = Abuf + 512*256;        // [512][256]
    float* phiT  = Bbuf + 512*256;        // [512][256]
    float* P     = phiT + 512*256;        // [1024][64]
    float* xg0   = P + 1024*64;           // [5120][512]
    float* xg1   = xg0 + 5120*512;        // [5120][512]
    unsigned short* wfrag  = (unsigned short*)(xg1 + 5120*512);  // 48*64*8
    unsigned short* ecwhi  = wfrag + 48*64*8;                    // 1024*64*8
    unsigned short* ecwlo  = ecwhi + 1024*64*8;                  // 1024*64*8
    unsigned short* lstmwf = ecwlo + 1024*64*8;                  // 3*128*64*8
    unsigned short* h0hi   = lstmwf + 3*128*64*8;                // [5120][128]
    unsigned short* h0lo   = h0hi + 5120*128;
    unsigned short* hbfA_hi = h0lo + 5120*128;                   // [1024][256]
    unsigned short* hbfA_lo = hbfA_hi + 1024*256;
    unsigned short* hbfB_hi = hbfA_lo + 1024*256;
    unsigned short* hbfB_lo = hbfB_hi + 1024*256;
    // total ~32 MB

    pn_wprep_kernel<<<48, 64, 0, stream>>>(pn_w2, pn_w3, wfrag);
    ec_wprep_kernel<<<1024, 64, 0, stream>>>(ec_tw, ec_pw, ecwhi, ecwlo);
    lstm_wprep_kernel<<<384, 64, 0, stream>>>(l0_whh, l1_wih, l1_whh, lstmwf);
    pointnet_mfma_kernel<<<1024, 256, 0, stream>>>(det_pc, trk_pc, pn_w1, pn_b1,
                                                   wfrag, pn_b2, pn_b3, hA);
    detmlp_kernel<<<512, 128, 0, stream>>>(det_box, mlp_w1, mlp_b1, mlp_w2, mlp_b2, hA);

    lstm_xg0_kernel<<<640, 512, 0, stream>>>(trk_box, l0_wih, xg0);
    lstm_mfma_kernel<0><<<32, 512, 0, stream>>>(lstmwf, xg0, l0_b, h0hi, h0lo, nullptr);
    lstm_xg1_kernel<<<dim3(80, 8), 256, 0, stream>>>(h0hi, h0lo, lstmwf + 128*64*8, xg1);
    lstm_mfma_kernel<1><<<32, 512, 0, stream>>>(lstmwf + 2*128*64*8, xg1, l1_b,
                                                nullptr, nullptr, hA);

    h2bf_kernel<<<256, 256, 0, stream>>>(hA, hbfA_hi, hbfA_lo);

    float* hcur = hA;  float* hnext = hB;
    unsigned short* chi = hbfA_hi; unsigned short* clo = hbfA_lo;
    unsigned short* nhi = hbfB_hi; unsigned short* nlo = hbfB_lo;
    for (int k = 0; k < 4; ++k) {
        const float* tb = ec_tb + (size_t)k * 256;
        const float* pb = ec_pb + (size_t)k * 256;
        ec_gemm_mfma_kernel<<<dim3(32, 8), 256, 0, stream>>>(
            chi, clo, ecwhi + (size_t)k*256*64*8, ecwlo + (size_t)k*256*64*8,
            tb, pb, Abuf, Bbuf, phiT, hnext, nhi, nlo);
        ec_colmax_kernel<<<dim3(32, 8), 256, 0, stream>>>(aff, Abuf, Bbuf, phiT, tb,
                                                          hnext, nhi, nlo);
        float* tf = hcur; hcur = hnext; hnext = tf;
        unsigned short* th = chi; chi = nhi; nhi = th;
        unsigned short* tl = clo; clo = nlo; nlo = tl;
    }

    headp_kernel<<<256, 256, 0, stream>>>(hcur, er_w1, P);
    pairwise_kernel<<<dim3(2, 512), 256, 0, stream>>>(P, aff, er_b1, er_w2, er_b2,
                                                      (float*)d_out);
}